// Round 12
// baseline (270.201 us; speedup 1.0000x reference)
//
#include <hip/hip_runtime.h>
#include <hip/hip_bf16.h>
#include <math.h>

// Problem constants
#define BB 2
#define CC 512
#define HH 32
#define WW 32
#define HWP 1024      // H*W
#define GG 8
#define DH 64
#define HD 8
#define WD 8
#define JJ 64         // HD*WD
#define BG 16         // BB*GG
#define EPS 1e-5f

typedef __attribute__((ext_vector_type(8))) short short8;
typedef __attribute__((ext_vector_type(4))) short s16x4;
typedef __attribute__((ext_vector_type(4))) float f32x4;
typedef __attribute__((ext_vector_type(4))) unsigned short u16x4;
typedef __attribute__((ext_vector_type(4))) unsigned int u32x4;

// RNE float -> bf16 bits
static __device__ __forceinline__ short f2bf(float x) {
    unsigned u = __builtin_bit_cast(unsigned, x);
    u += 0x7FFFu + ((u >> 16) & 1u);
    return (short)(u >> 16);
}
static __device__ __forceinline__ float bf2f(unsigned short h) {
    return __builtin_bit_cast(float, (unsigned)h << 16);
}

// ---------------- K2: weight-pack phase + q grouped 1x1 conv via MFMA -> qt bf16 ----------------
// phase 0: pack qw|out_w|mlp_w1|mlp_w2 -> wp (bf16) and cpb_w2 -> w2p (frag order).
//   Race-free: this kernel stages its own A from fp32 qw; all wp/w2p consumers
//   launch later (stream order).
// phase 1: q GEMM (BN1 folded in B-staging), output transposed qt[bg][i][ch] bf16.
__global__ __launch_bounds__(256) void k_qgemm(
    const float* __restrict__ x, const float* __restrict__ g1,
    const float* __restrict__ b1, const float* __restrict__ qw,
    const float* __restrict__ ow, const float* __restrict__ w1,
    const float* __restrict__ w2, const float* __restrict__ cw2,
    unsigned short* __restrict__ wp, unsigned short* __restrict__ w2p,
    unsigned short* __restrict__ qt) {
    __shared__ __align__(16) short As[64][72];
    __shared__ __align__(16) short Bs[64][72];
    int tid = threadIdx.x;
    // ---- phase 0: weight packing (grid-strided over 65536 threads) ----
    for (int idx = blockIdx.x * 256 + tid; idx < 2408448; idx += 65536) {
        if (idx < 2392064) {
            float v;
            if (idx < 32768) v = qw[idx];
            else if (idx < 294912) v = ow[idx - 32768];
            else if (idx < 1343488) v = w1[idx - 294912];
            else v = w2[idx - 1343488];
            wp[idx] = (unsigned short)f2bf(v);
        } else {
            int i2 = idx - 2392064;
            int k = i2 >> 7, n = i2 & 127;
            int dest = ((((n >> 4) * 4 + (k >> 5)) * 64) + (((k >> 3) & 3) * 16) + (n & 15)) * 8 + (k & 7);
            w2p[dest] = (unsigned short)f2bf(cw2[i2]);
        }
    }
    // ---- phase 1: q GEMM ----
    int blk = blockIdx.x;
    int bg = blk >> 4, nt = blk & 15;
    int b = bg >> 3, g = bg & 7;
    int i0 = nt * 64;
    int lane = tid & 63, wv = tid >> 6;
    int wm = (wv >> 1) * 32, wn = (wv & 1) * 32;
    int l15 = lane & 15, quad = lane >> 4;
    const float invs = 1.0f / sqrtf(1.0f + EPS);
    {
        int c4 = (tid & 15) * 4;
        int ob = tid >> 4;
#pragma unroll
        for (int p = 0; p < 4; p++) {
            int o = ob + p * 16;
            f32x4 v = *(const f32x4*)(qw + (size_t)(g * 64 + o) * 64 + c4);
            s16x4 s = {f2bf(v.x), f2bf(v.y), f2bf(v.z), f2bf(v.w)};
            *(s16x4*)&As[o][c4] = s;
        }
    }
    {
        int i4 = (tid & 15) * 4;
        int cb = tid >> 4;
#pragma unroll
        for (int p = 0; p < 4; p++) {
            int c = cb + p * 16;
            f32x4 v = *(const f32x4*)(x + (size_t)(b * CC + g * 64 + c) * HWP + i0 + i4);
            float sc = g1[g * 64 + c] * invs;
            float sh = b1[g * 64 + c];
            Bs[i4 + 0][c] = f2bf(fmaf(v.x, sc, sh));
            Bs[i4 + 1][c] = f2bf(fmaf(v.y, sc, sh));
            Bs[i4 + 2][c] = f2bf(fmaf(v.z, sc, sh));
            Bs[i4 + 3][c] = f2bf(fmaf(v.w, sc, sh));
        }
    }
    __syncthreads();
    f32x4 acc[2][2];
#pragma unroll
    for (int a = 0; a < 2; a++)
#pragma unroll
        for (int c = 0; c < 2; c++) acc[a][c] = (f32x4){0.f, 0.f, 0.f, 0.f};
#pragma unroll
    for (int ks = 0; ks < 2; ks++) {
        short8 af0 = *(const short8*)&As[wm + l15][ks * 32 + quad * 8];
        short8 af1 = *(const short8*)&As[wm + 16 + l15][ks * 32 + quad * 8];
        short8 bf0 = *(const short8*)&Bs[wn + l15][ks * 32 + quad * 8];
        short8 bf1 = *(const short8*)&Bs[wn + 16 + l15][ks * 32 + quad * 8];
        acc[0][0] = __builtin_amdgcn_mfma_f32_16x16x32_bf16(af0, bf0, acc[0][0], 0, 0, 0);
        acc[0][1] = __builtin_amdgcn_mfma_f32_16x16x32_bf16(af0, bf1, acc[0][1], 0, 0, 0);
        acc[1][0] = __builtin_amdgcn_mfma_f32_16x16x32_bf16(af1, bf0, acc[1][0], 0, 0, 0);
        acc[1][1] = __builtin_amdgcn_mfma_f32_16x16x32_bf16(af1, bf1, acc[1][1], 0, 0, 0);
    }
    // transpose via LDS (reuse As) -> coalesced qt[bg][i][ch] bf16 stores
    __syncthreads();
#pragma unroll
    for (int im = 0; im < 2; im++)
#pragma unroll
        for (int r = 0; r < 4; r++) {
            int m = wm + im * 16 + quad * 4 + r;
#pragma unroll
            for (int in_ = 0; in_ < 2; in_++) {
                int n = wn + in_ * 16 + l15;
                As[n][m] = f2bf(acc[im][in_][r]);
            }
        }
    __syncthreads();
    {
        int n = tid >> 2;
        int c0 = (tid & 3) * 16;
        short8 a = *(const short8*)&As[n][c0];
        short8 c = *(const short8*)&As[n][c0 + 8];
        unsigned short* dst = qt + ((size_t)bg * 1024 + i0 + n) * 64 + c0;
        *(short8*)dst = a;
        *(short8*)(dst + 8) = c;
    }
}

// ---------------- K3+K4+K5 fused v2: block = (bg, hd), 512 threads (wd = wave, ch = lane) ----------------
// Stage the 6 needed qt rows in LDS once; 8 wd-waves compute conv/offset/sample/kvconv.
__global__ __launch_bounds__(512) void k_offskv(
    const unsigned short* __restrict__ qt, const float* __restrict__ dww,
    const float* __restrict__ dwb, const float* __restrict__ pw,
    const float* __restrict__ x, const float* __restrict__ g1,
    const float* __restrict__ b1, const float* __restrict__ kw,
    const float* __restrict__ vw, float* __restrict__ vgrid,
    float* __restrict__ kk, float* __restrict__ vv) {
    __shared__ __align__(16) short qs[6][2048];   // [kh][wi*64+ch], 24 KB
    __shared__ float sm[8][64];
    int blk = blockIdx.x;          // bg*8 + hd
    int bg = blk >> 3, hd = blk & 7;
    int g = bg & 7, b = bg >> 3;
    int tid = threadIdx.x;
    int wd = tid >> 6, ch = tid & 63;
    // stage 6 qt rows (hin = hd*4-1 .. hd*4+4), skip invalid
    {
        const unsigned short* qb = qt + (size_t)bg * 65536;
#pragma unroll
        for (int r = 0; r < 6; r++) {
            int hin = hd * 4 - 1 + r;
            if (hin >= 0 && hin < HH) {
                u16x4 v = *(const u16x4*)(qb + hin * 2048 + tid * 4);
                *(u16x4*)&qs[r][tid * 4] = v;
            }
        }
    }
    __syncthreads();
    // depthwise 6x6 s4 conv from LDS
    float acc = 0.f;
#pragma unroll
    for (int kh = 0; kh < 6; kh++) {
        int hin = hd * 4 - 1 + kh;
        if (hin < 0 || hin >= HH) continue;
#pragma unroll
        for (int kw_ = 0; kw_ < 6; kw_++) {
            int win = wd * 4 - 1 + kw_;
            if (win < 0 || win >= WW) continue;
            acc = fmaf(bf2f(qs[kh][win * 64 + ch]), dww[ch * 36 + kh * 6 + kw_], acc);
        }
    }
    acc += dwb[ch];
    float ge = 0.5f * acc * (1.0f + erff(acc * 0.7071067811865475f));
    float p0 = ge * pw[ch];
    float p1 = ge * pw[64 + ch];
#pragma unroll
    for (int off = 32; off; off >>= 1) {
        p0 += __shfl_xor(p0, off);
        p1 += __shfl_xor(p1, off);
    }
    int j = hd * 8 + wd;
    float nx = 2.0f * ((float)wd + tanhf(p0) * 4.0f) / 7.0f - 1.0f;
    float ny = 2.0f * ((float)hd + tanhf(p1) * 4.0f) / 7.0f - 1.0f;
    if (ch == 0) {
        vgrid[(bg * 64 + j) * 2] = nx;
        vgrid[(bg * 64 + j) * 2 + 1] = ny;
    }
    // sample (BN1 folded)
    {
        int cg = g * 64 + ch;
        const float invs = 1.0f / sqrtf(1.0f + EPS);
        float s = g1[cg] * invs;
        float bv = b1[cg];
        float gx = (nx + 1.0f) * 16.0f - 0.5f;
        float gy = (ny + 1.0f) * 16.0f - 0.5f;
        float x0f = floorf(gx), y0f = floorf(gy);
        float wx = gx - x0f, wy = gy - y0f;
        int x0 = (int)x0f, y0 = (int)y0f;
        const float* im = x + (size_t)(b * CC + cg) * HWP;
        float sx = 0.f, sw = 0.f;
        float w00 = (1 - wx) * (1 - wy), w01 = wx * (1 - wy);
        float w10 = (1 - wx) * wy, w11 = wx * wy;
        if (x0 >= 0 && x0 < WW && y0 >= 0 && y0 < HH)                 { sx += w00 * im[y0 * WW + x0];           sw += w00; }
        if (x0 + 1 >= 0 && x0 + 1 < WW && y0 >= 0 && y0 < HH)         { sx += w01 * im[y0 * WW + x0 + 1];       sw += w01; }
        if (x0 >= 0 && x0 < WW && y0 + 1 >= 0 && y0 + 1 < HH)         { sx += w10 * im[(y0 + 1) * WW + x0];     sw += w10; }
        if (x0 + 1 >= 0 && x0 + 1 < WW && y0 + 1 >= 0 && y0 + 1 < HH) { sx += w11 * im[(y0 + 1) * WW + x0 + 1]; sw += w11; }
        sm[wd][ch] = s * sx + bv * sw;
    }
    __syncthreads();
    // k/v grouped conv (lane = output channel)
    const float* kwr = kw + (size_t)(g * 64 + ch) * 64;
    const float* vwr = vw + (size_t)(g * 64 + ch) * 64;
    float ak = 0.f, av = 0.f;
#pragma unroll
    for (int c = 0; c < 64; c++) {
        float tv = sm[wd][c];
        ak = fmaf(tv, kwr[c], ak);
        av = fmaf(tv, vwr[c], av);
    }
    kk[(size_t)bg * 4096 + j * 64 + ch] = ak;
    vv[(size_t)bg * 4096 + j * 64 + ch] = av;
}

// ---------------- K6: CPB bias MLP via bf16 MFMA (v6 + bf16 bias output) ----------------
__global__ __launch_bounds__(256) void k_cpb(
    const float* __restrict__ vgrid, const unsigned short* __restrict__ w2p,
    const float* __restrict__ w1, const float* __restrict__ b1,
    const float* __restrict__ b2, const float* __restrict__ w3,
    const float* __restrict__ b3, unsigned short* __restrict__ bias) {
    __shared__ __align__(16) short w2fs[16384];   // exactly 32768 B
    int tid = threadIdx.x;
    {
        const u32x4* src = (const u32x4*)w2p;
        u32x4* dst = (u32x4*)w2fs;
        for (int c = tid; c < 2048; c += 256) dst[c] = src[c];
    }
    float bias3 = b3[0];
    __syncthreads();

    int lane = tid & 63;
    int wv = tid >> 6;
    int l15 = lane & 15;
    int quad = lane >> 4;

#pragma unroll 1
    for (int it = 0; it < 4; it++) {
        int p = (blockIdx.x * 4 + it) * 4 + wv;
        int cofs = (int)((unsigned)p >> 20);   // runtime 0, compiler-opaque (anti-LICM)
        int bg = p >> 11;
        int i = (p >> 1) & 1023;
        int jbase = (p & 1) * 32;
        int hi = i >> 5, wi = i & 31;
        float qx = 2.0f * (float)wi / 31.0f - 1.0f;
        float qy = 2.0f * (float)hi / 31.0f - 1.0f;

        int jA = jbase + l15;
        float gkxA = vgrid[(bg * 64 + jA) * 2];
        float gkyA = vgrid[(bg * 64 + jA) * 2 + 1];
        float gkxB = vgrid[(bg * 64 + jA + 16) * 2];
        float gkyB = vgrid[(bg * 64 + jA + 16) * 2 + 1];
        float p0 = qx - gkxA, p1 = qy - gkyA;
        float s0a = copysignf(log1pf(fabsf(p0)), p0);
        float s1a = copysignf(log1pf(fabsf(p1)), p1);
        p0 = qx - gkxB; p1 = qy - gkyB;
        float s0b = copysignf(log1pf(fabsf(p0)), p0);
        float s1b = copysignf(log1pf(fabsf(p1)), p1);

        short8 hA[4], hB[4];
#pragma unroll
        for (int kc = 0; kc < 4; kc++) {
            f32x4 cu0 = *(const f32x4*)(w1 + cofs + kc * 32 + quad * 8);
            f32x4 cu1 = *(const f32x4*)(w1 + cofs + kc * 32 + quad * 8 + 4);
            f32x4 cv0 = *(const f32x4*)(w1 + cofs + 128 + kc * 32 + quad * 8);
            f32x4 cv1 = *(const f32x4*)(w1 + cofs + 128 + kc * 32 + quad * 8 + 4);
            f32x4 cb0 = *(const f32x4*)(b1 + cofs + kc * 32 + quad * 8);
            f32x4 cb1 = *(const f32x4*)(b1 + cofs + kc * 32 + quad * 8 + 4);
            u32x4 pa, pb;
#pragma unroll
            for (int j2 = 0; j2 < 4; j2++) {
                int e0 = 2 * j2, e1 = 2 * j2 + 1;
                float u0 = (e0 < 4) ? cu0[e0] : cu1[e0 - 4];
                float u1 = (e1 < 4) ? cu0[e1] : cu1[e1 - 4];
                float v0 = (e0 < 4) ? cv0[e0] : cv1[e0 - 4];
                float v1 = (e1 < 4) ? cv0[e1] : cv1[e1 - 4];
                float c0 = (e0 < 4) ? cb0[e0] : cb1[e0 - 4];
                float c1 = (e1 < 4) ? cb0[e1] : cb1[e1 - 4];
                unsigned a0 = __builtin_bit_cast(unsigned,
                    fmaxf(fmaf(s0a, u0, fmaf(s1a, v0, c0)), 0.f)) + 0x8000u;
                unsigned a1 = __builtin_bit_cast(unsigned,
                    fmaxf(fmaf(s0a, u1, fmaf(s1a, v1, c1)), 0.f)) + 0x8000u;
                pa[j2] = __builtin_amdgcn_perm(a1, a0, 0x07060302);
                unsigned b0 = __builtin_bit_cast(unsigned,
                    fmaxf(fmaf(s0b, u0, fmaf(s1b, v0, c0)), 0.f)) + 0x8000u;
                unsigned b1_ = __builtin_bit_cast(unsigned,
                    fmaxf(fmaf(s0b, u1, fmaf(s1b, v1, c1)), 0.f)) + 0x8000u;
                pb[j2] = __builtin_amdgcn_perm(b1_, b0, 0x07060302);
            }
            hA[kc] = __builtin_bit_cast(short8, pa);
            hB[kc] = __builtin_bit_cast(short8, pb);
        }

        float psumA = 0.f, psumB = 0.f;
#pragma unroll 2
        for (int nt = 0; nt < 8; nt++) {
            f32x4 accA = (f32x4){0.f, 0.f, 0.f, 0.f};
            f32x4 accB = (f32x4){0.f, 0.f, 0.f, 0.f};
#pragma unroll
            for (int kc = 0; kc < 4; kc++) {
                short8 af = *(const short8*)(w2fs + (((nt * 4 + kc) * 64) + lane) * 8);
                accA = __builtin_amdgcn_mfma_f32_16x16x32_bf16(af, hA[kc], accA, 0, 0, 0);
                accB = __builtin_amdgcn_mfma_f32_16x16x32_bf16(af, hB[kc], accB, 0, 0, 0);
            }
            f32x4 b2q = *(const f32x4*)(b2 + cofs + nt * 16 + quad * 4);
            f32x4 w3q = *(const f32x4*)(w3 + cofs + nt * 16 + quad * 4);
#pragma unroll
            for (int r = 0; r < 4; r++) {
                psumA = fmaf(fmaxf(accA[r] + b2q[r], 0.f), w3q[r], psumA);
                psumB = fmaf(fmaxf(accB[r] + b2q[r], 0.f), w3q[r], psumB);
            }
        }
        psumA += __shfl_xor(psumA, 16);
        psumA += __shfl_xor(psumA, 32);
        psumB += __shfl_xor(psumB, 16);
        psumB += __shfl_xor(psumB, 32);
        if (quad == 0) {
            bias[(size_t)(p * 2 + 0) * 16 + l15] = (unsigned short)f2bf(psumA + bias3);
            bias[(size_t)(p * 2 + 1) * 16 + l15] = (unsigned short)f2bf(psumB + bias3);
        }
    }
}

// ---------------- K7: attention via MFMA (bf16 bias) ----------------
__global__ __launch_bounds__(256) void k_attn(
    const unsigned short* __restrict__ qt, const float* __restrict__ kk,
    const float* __restrict__ vv, const unsigned short* __restrict__ bias,
    unsigned short* __restrict__ ao) {
    __shared__ __align__(16) short Ks[64][72];
    __shared__ __align__(16) short Vt[64][72];
    __shared__ __align__(16) short Qs[64][72];
    __shared__ __align__(16) short Ps[4][16][72];
    int blk = blockIdx.x;
    int bg = blk >> 4;
    int chunk = blk & 15;
    int i0 = chunk * 64;
    int b = bg >> 3, g = bg & 7;
    int tid = threadIdx.x, lane = tid & 63, wv = tid >> 6;
    int l15 = lane & 15, quad = lane >> 4;

    const float* kbase = kk + (size_t)bg * 4096;
    const float* vbase = vv + (size_t)bg * 4096;
#pragma unroll
    for (int it = 0; it < 4; it++) {
        int e4 = it * 1024 + tid * 4;
        int j = e4 >> 6, d = e4 & 63;
        f32x4 k4 = *(const f32x4*)(kbase + e4);
        s16x4 s = {f2bf(k4.x), f2bf(k4.y), f2bf(k4.z), f2bf(k4.w)};
        *(s16x4*)&Ks[j][d] = s;
        f32x4 v4 = *(const f32x4*)(vbase + e4);
        Vt[d + 0][j] = f2bf(v4.x);
        Vt[d + 1][j] = f2bf(v4.y);
        Vt[d + 2][j] = f2bf(v4.z);
        Vt[d + 3][j] = f2bf(v4.w);
    }
    {
        const unsigned short* qtb = qt + ((size_t)bg * 1024 + i0) * 64;
#pragma unroll
        for (int it = 0; it < 4; it++) {
            int e4 = it * 1024 + tid * 4;
            int i = e4 >> 6, d = e4 & 63;
            u16x4 v = *(const u16x4*)(qtb + e4);
            *(u16x4*)&Qs[i][d] = v;
        }
    }
    __syncthreads();

    int iw = wv * 16;
    f32x4 Sacc[4];
#pragma unroll
    for (int nt = 0; nt < 4; nt++) Sacc[nt] = (f32x4){0.f, 0.f, 0.f, 0.f};
#pragma unroll
    for (int ks = 0; ks < 2; ks++) {
        short8 aq = *(const short8*)&Qs[iw + l15][quad * 8 + ks * 32];
#pragma unroll
        for (int nt = 0; nt < 4; nt++) {
            short8 bk = *(const short8*)&Ks[nt * 16 + l15][quad * 8 + ks * 32];
            Sacc[nt] = __builtin_amdgcn_mfma_f32_16x16x32_bf16(aq, bk, Sacc[nt], 0, 0, 0);
        }
    }
    const unsigned short* bp = bias + ((size_t)bg * 1024 + i0 + iw + quad * 4) * 64 + l15;
    float Sv[4][4];
#pragma unroll
    for (int nt = 0; nt < 4; nt++)
#pragma unroll
        for (int r = 0; r < 4; r++)
            Sv[nt][r] = fmaf(Sacc[nt][r], 0.125f, bf2f(bp[r * 64 + nt * 16]));
#pragma unroll
    for (int r = 0; r < 4; r++) {
        float m = fmaxf(fmaxf(Sv[0][r], Sv[1][r]), fmaxf(Sv[2][r], Sv[3][r]));
        m = fmaxf(m, __shfl_xor(m, 1));
        m = fmaxf(m, __shfl_xor(m, 2));
        m = fmaxf(m, __shfl_xor(m, 4));
        m = fmaxf(m, __shfl_xor(m, 8));
        float l = 0.f;
#pragma unroll
        for (int nt = 0; nt < 4; nt++) { Sv[nt][r] = expf(Sv[nt][r] - m); l += Sv[nt][r]; }
        l += __shfl_xor(l, 1);
        l += __shfl_xor(l, 2);
        l += __shfl_xor(l, 4);
        l += __shfl_xor(l, 8);
        float inv = 1.0f / l;
#pragma unroll
        for (int nt = 0; nt < 4; nt++)
            Ps[wv][quad * 4 + r][nt * 16 + l15] = f2bf(Sv[nt][r] * inv);
    }
    f32x4 Oacc[4];
#pragma unroll
    for (int nt = 0; nt < 4; nt++) Oacc[nt] = (f32x4){0.f, 0.f, 0.f, 0.f};
#pragma unroll
    for (int ks = 0; ks < 2; ks++) {
        short8 ap = *(const short8*)&Ps[wv][l15][quad * 8 + ks * 32];
#pragma unroll
        for (int nt = 0; nt < 4; nt++) {
            short8 bv = *(const short8*)&Vt[nt * 16 + l15][quad * 8 + ks * 32];
            Oacc[nt] = __builtin_amdgcn_mfma_f32_16x16x32_bf16(ap, bv, Oacc[nt], 0, 0, 0);
        }
    }
    __syncthreads();
#pragma unroll
    for (int nt = 0; nt < 4; nt++) {
        s16x4 o4 = {f2bf(Oacc[nt][0]), f2bf(Oacc[nt][1]), f2bf(Oacc[nt][2]), f2bf(Oacc[nt][3])};
        *(s16x4*)&Qs[nt * 16 + l15][iw + quad * 4] = o4;
    }
    __syncthreads();
    {
        int d = tid >> 2;
        int ic = (tid & 3) * 16;
        short8 a = *(const short8*)&Qs[d][ic];
        short8 c = *(const short8*)&Qs[d][ic + 8];
        unsigned short* dst = ao + (size_t)(b * CC + g * 64 + d) * HWP + i0 + ic;
        *(short8*)dst = a;
        *(short8*)(dst + 8) = c;
    }
}

// ---------------- K8/K10/K11: tiled bf16-MFMA GEMM (A+B bf16, BK-templated) ----------------
// EPI 0/2: +resid fp32. EPI 1: gelu bf16. EPI 3: +resid fp32 AND bf16(BN2) to out2.
template<int EPI, int KD, int BK, int MT>
__global__ __launch_bounds__(256) void k_gemm(
    const unsigned short* __restrict__ A, const unsigned short* __restrict__ Bh,
    const float* __restrict__ resid, const float* __restrict__ bias,
    void* __restrict__ outp, unsigned short* __restrict__ out2,
    const float* __restrict__ bns, const float* __restrict__ bnb) {
    constexpr int MM = MT * 64;
    __shared__ __align__(16) short As[64][BK + 8];
    __shared__ __align__(16) short Bs[64][BK + 8];
    int tid = threadIdx.x;
    int blk = blockIdx.x;
    int mt = blk & (MT - 1);
    int nb = blk / MT;              // 0..31
    int bb = nb >> 4, nt = nb & 15;
    int m0 = mt * 64, i0 = nt * 64;
    int lane = tid & 63, wv = tid >> 6;
    int wm = (wv >> 1) * 32, wn = (wv & 1) * 32;
    int l15 = lane & 15, quad = lane >> 4;
    const unsigned short* Af = A + (size_t)m0 * KD;
    const float invs = 1.0f / sqrtf(1.0f + EPS);

    f32x4 acc[2][2];
#pragma unroll
    for (int a = 0; a < 2; a++)
#pragma unroll
        for (int c = 0; c < 2; c++) acc[a][c] = (f32x4){0.f, 0.f, 0.f, 0.f};

    for (int k0 = 0; k0 < KD; k0 += BK) {
        __syncthreads();
        {
            int kk4 = (tid & (BK / 4 - 1)) * 4;
            int myb = tid / (BK / 4);
            constexpr int RP = 256 / (BK / 4);     // rows per pass
#pragma unroll
            for (int p = 0; p < 64 / RP; p++) {
                int my = myb + p * RP;
                u16x4 v = *(const u16x4*)(Af + (size_t)my * KD + k0 + kk4);
                *(u16x4*)&As[my][kk4] = v;
            }
        }
        {
            int i4 = (tid & 15) * 4;
            int kyb = tid >> 4;
#pragma unroll
            for (int p = 0; p < BK / 16; p++) {
                int ky = kyb + p * 16;
                size_t goff = (size_t)bb * KD * HWP + (size_t)(k0 + ky) * HWP + i0 + i4;
                u16x4 v = *(const u16x4*)(Bh + goff);
                Bs[i4 + 0][ky] = (short)v.x;
                Bs[i4 + 1][ky] = (short)v.y;
                Bs[i4 + 2][ky] = (short)v.z;
                Bs[i4 + 3][ky] = (short)v.w;
            }
        }
        __syncthreads();
#pragma unroll
        for (int ks = 0; ks < BK / 32; ks++) {
            short8 af0 = *(const short8*)&As[wm + l15][ks * 32 + quad * 8];
            short8 af1 = *(const short8*)&As[wm + 16 + l15][ks * 32 + quad * 8];
            short8 bf0 = *(const short8*)&Bs[wn + l15][ks * 32 + quad * 8];
            short8 bf1 = *(const short8*)&Bs[wn + 16 + l15][ks * 32 + quad * 8];
            acc[0][0] = __builtin_amdgcn_mfma_f32_16x16x32_bf16(af0, bf0, acc[0][0], 0, 0, 0);
            acc[0][1] = __builtin_amdgcn_mfma_f32_16x16x32_bf16(af0, bf1, acc[0][1], 0, 0, 0);
            acc[1][0] = __builtin_amdgcn_mfma_f32_16x16x32_bf16(af1, bf0, acc[1][0], 0, 0, 0);
            acc[1][1] = __builtin_amdgcn_mfma_f32_16x16x32_bf16(af1, bf1, acc[1][1], 0, 0, 0);
        }
    }

    float* outF = (float*)outp;
    unsigned short* outH = (unsigned short*)outp;
#pragma unroll
    for (int im = 0; im < 2; im++) {
#pragma unroll
        for (int r = 0; r < 4; r++) {
            int m = m0 + wm + im * 16 + quad * 4 + r;
            float bv = bias[m];
#pragma unroll
            for (int in_ = 0; in_ < 2; in_++) {
                int n = i0 + wn + in_ * 16 + l15;
                size_t idx = ((size_t)bb * MM + m) * HWP + n;
                float v = acc[im][in_][r] + bv;
                if constexpr (EPI == 1) {
                    float ge = 0.5f * v * (1.0f + erff(v * 0.7071067811865475f));
                    outH[idx] = (unsigned short)f2bf(ge);
                } else if constexpr (EPI == 3) {
                    float vr = v + resid[idx];
                    outF[idx] = vr;
                    out2[idx] = (unsigned short)f2bf(fmaf(vr, bns[m] * invs, bnb[m]));
                } else {
                    outF[idx] = v + resid[idx];
                }
            }
        }
    }
}

extern "C" void kernel_launch(void* const* d_in, const int* in_sizes, int n_in,
                              void* d_out, int out_size, void* d_ws, size_t ws_size,
                              hipStream_t stream) {
    const float* x      = (const float*)d_in[0];
    const float* bn1_g  = (const float*)d_in[1];
    const float* bn1_b  = (const float*)d_in[2];
    const float* bn2_g  = (const float*)d_in[3];
    const float* bn2_b  = (const float*)d_in[4];
    const float* qw     = (const float*)d_in[5];
    const float* kw     = (const float*)d_in[6];
    const float* vw     = (const float*)d_in[7];
    const float* out_w  = (const float*)d_in[8];
    const float* out_b  = (const float*)d_in[9];
    const float* off_dw_w = (const float*)d_in[10];
    const float* off_dw_b = (const float*)d_in[11];
    const float* off_pw_w = (const float*)d_in[12];
    const float* cpb_w1 = (const float*)d_in[13];
    const float* cpb_b1 = (const float*)d_in[14];
    const float* cpb_w2 = (const float*)d_in[15];
    const float* cpb_b2 = (const float*)d_in[16];
    const float* cpb_w3 = (const float*)d_in[17];
    const float* cpb_b3 = (const float*)d_in[18];
    const float* mlp_w1 = (const float*)d_in[19];
    const float* mlp_b1 = (const float*)d_in[20];
    const float* mlp_w2 = (const float*)d_in[21];
    const float* mlp_b2 = (const float*)d_in[22];

    float* ws = (float*)d_ws;
    unsigned short* qt = (unsigned short*)(ws + 1048576);   // 1,048,576 bf16
    float* vgrid = ws + 2097152;      // 2,048
    float* kk    = ws + 2164736;      // 65,536
    float* vv    = ws + 2230272;      // 65,536
    unsigned short* w2p = (unsigned short*)(ws + 2295808);  // 16,384 bf16
    unsigned short* ao  = (unsigned short*)(ws + 2312192);  // 1,048,576 bf16
    unsigned short* xn2 = (unsigned short*)(ws + 2836480);  // 1,048,576 bf16
    float* xo    = ws + 3360768;      // 1,048,576 floats
    float* h1of  = ws + 4409344;      // bias bf16 (1M ushorts), then h1o bf16 (4M ushorts)
    unsigned short* biasb = (unsigned short*)h1of;          // consumed by k_attn before g1 writes h1o
    unsigned short* h1o = (unsigned short*)h1of;
    unsigned short* wp  = (unsigned short*)(ws + 6506496);  // 2,392,064 ushorts
    unsigned short* owp  = wp + 32768;
    unsigned short* w1p  = wp + 294912;
    unsigned short* w2mp = wp + 1343488;

    // 7 launches (was 9): wpack folded into k_qgemm phase 0; offskv restructured.
    hipLaunchKernelGGL(k_qgemm, dim3(256), dim3(256), 0, stream,
                       x, bn1_g, bn1_b, qw, out_w, mlp_w1, mlp_w2, cpb_w2, wp, w2p, qt);
    hipLaunchKernelGGL(k_offskv, dim3(128), dim3(512), 0, stream,
                       qt, off_dw_w, off_dw_b, off_pw_w, x, bn1_g, bn1_b, kw, vw,
                       vgrid, kk, vv);
    hipLaunchKernelGGL(k_cpb, dim3(2048), dim3(256), 0, stream,
                       vgrid, w2p, cpb_w1, cpb_b1, cpb_b2, cpb_w3, cpb_b3, biasb);
    hipLaunchKernelGGL(k_attn, dim3(256), dim3(256), 0, stream, qt, kk, vv, biasb, ao);
    // out projection: M=512, K=512 (BK=128), B=ao bf16, resid=x -> xo + xn2(BN2 bf16)
    k_gemm<3, 512, 128, 8><<<dim3(256), dim3(256), 0, stream>>>(
        owp, ao, x, out_b, xo, xn2, bn2_g, bn2_b);
    // MLP1: M=2048, K=512 (BK=128), B=xn2 bf16, gelu -> h1o bf16
    k_gemm<1, 512, 128, 32><<<dim3(1024), dim3(256), 0, stream>>>(
        w1p, xn2, nullptr, mlp_b1, h1o, nullptr, nullptr, nullptr);
    // MLP2: M=512, K=2048 (BK=128), B=h1o bf16, resid=xo -> d_out
    k_gemm<2, 2048, 128, 8><<<dim3(256), dim3(256), 0, stream>>>(
        w2mp, h1o, xo, mlp_b2, d_out, nullptr, nullptr, nullptr);
}

// Round 13
// 255.638 us; speedup vs baseline: 1.0570x; 1.0570x over previous
//
#include <hip/hip_runtime.h>
#include <hip/hip_bf16.h>
#include <math.h>

// Problem constants
#define BB 2
#define CC 512
#define HH 32
#define WW 32
#define HWP 1024      // H*W
#define GG 8
#define DH 64
#define HD 8
#define WD 8
#define JJ 64         // HD*WD
#define BG 16         // BB*GG
#define EPS 1e-5f

typedef __attribute__((ext_vector_type(8))) short short8;
typedef __attribute__((ext_vector_type(4))) short s16x4;
typedef __attribute__((ext_vector_type(4))) float f32x4;
typedef __attribute__((ext_vector_type(4))) unsigned short u16x4;
typedef __attribute__((ext_vector_type(4))) unsigned int u32x4;

// RNE float -> bf16 bits
static __device__ __forceinline__ short f2bf(float x) {
    unsigned u = __builtin_bit_cast(unsigned, x);
    u += 0x7FFFu + ((u >> 16) & 1u);
    return (short)(u >> 16);
}
static __device__ __forceinline__ float bf2f(unsigned short h) {
    return __builtin_bit_cast(float, (unsigned)h << 16);
}

// ---------------- K0: pre-pack ALL weights to bf16 (separate launch — r12 fusion regressed) ----------------
__global__ void k_wpack(const float* __restrict__ qw, const float* __restrict__ ow,
                        const float* __restrict__ w1, const float* __restrict__ w2,
                        const float* __restrict__ cw2, unsigned short* __restrict__ wp,
                        unsigned short* __restrict__ w2p) {
    int idx = blockIdx.x * 256 + threadIdx.x;
    if (idx < 2392064) {
        float v;
        if (idx < 32768) v = qw[idx];
        else if (idx < 294912) v = ow[idx - 32768];
        else if (idx < 1343488) v = w1[idx - 294912];
        else v = w2[idx - 1343488];
        wp[idx] = (unsigned short)f2bf(v);
    } else if (idx < 2408448) {
        int i2 = idx - 2392064;
        int k = i2 >> 7, n = i2 & 127;
        int dest = ((((n >> 4) * 4 + (k >> 5)) * 64) + (((k >> 3) & 3) * 16) + (n & 15)) * 8 + (k & 7);
        w2p[dest] = (unsigned short)f2bf(cw2[i2]);
    }
}

// ---------------- K2: q grouped 1x1 conv via MFMA -> qt[bg][i][ch] bf16 ----------------
__global__ __launch_bounds__(256) void k_qgemm(
    const float* __restrict__ x, const float* __restrict__ g1,
    const float* __restrict__ b1, const unsigned short* __restrict__ qwp,
    unsigned short* __restrict__ qt) {
    __shared__ __align__(16) short As[64][72];
    __shared__ __align__(16) short Bs[64][72];
    int blk = blockIdx.x;
    int bg = blk >> 4, nt = blk & 15;
    int b = bg >> 3, g = bg & 7;
    int i0 = nt * 64;
    int tid = threadIdx.x, lane = tid & 63, wv = tid >> 6;
    int wm = (wv >> 1) * 32, wn = (wv & 1) * 32;
    int l15 = lane & 15, quad = lane >> 4;
    const float invs = 1.0f / sqrtf(1.0f + EPS);
    {
        int c4 = (tid & 15) * 4;
        int ob = tid >> 4;
#pragma unroll
        for (int p = 0; p < 4; p++) {
            int o = ob + p * 16;
            u16x4 v = *(const u16x4*)(qwp + (size_t)(g * 64 + o) * 64 + c4);
            *(u16x4*)&As[o][c4] = v;
        }
    }
    {
        int i4 = (tid & 15) * 4;
        int cb = tid >> 4;
#pragma unroll
        for (int p = 0; p < 4; p++) {
            int c = cb + p * 16;
            f32x4 v = *(const f32x4*)(x + (size_t)(b * CC + g * 64 + c) * HWP + i0 + i4);
            float sc = g1[g * 64 + c] * invs;
            float sh = b1[g * 64 + c];
            Bs[i4 + 0][c] = f2bf(fmaf(v.x, sc, sh));
            Bs[i4 + 1][c] = f2bf(fmaf(v.y, sc, sh));
            Bs[i4 + 2][c] = f2bf(fmaf(v.z, sc, sh));
            Bs[i4 + 3][c] = f2bf(fmaf(v.w, sc, sh));
        }
    }
    __syncthreads();
    f32x4 acc[2][2];
#pragma unroll
    for (int a = 0; a < 2; a++)
#pragma unroll
        for (int c = 0; c < 2; c++) acc[a][c] = (f32x4){0.f, 0.f, 0.f, 0.f};
#pragma unroll
    for (int ks = 0; ks < 2; ks++) {
        short8 af0 = *(const short8*)&As[wm + l15][ks * 32 + quad * 8];
        short8 af1 = *(const short8*)&As[wm + 16 + l15][ks * 32 + quad * 8];
        short8 bf0 = *(const short8*)&Bs[wn + l15][ks * 32 + quad * 8];
        short8 bf1 = *(const short8*)&Bs[wn + 16 + l15][ks * 32 + quad * 8];
        acc[0][0] = __builtin_amdgcn_mfma_f32_16x16x32_bf16(af0, bf0, acc[0][0], 0, 0, 0);
        acc[0][1] = __builtin_amdgcn_mfma_f32_16x16x32_bf16(af0, bf1, acc[0][1], 0, 0, 0);
        acc[1][0] = __builtin_amdgcn_mfma_f32_16x16x32_bf16(af1, bf0, acc[1][0], 0, 0, 0);
        acc[1][1] = __builtin_amdgcn_mfma_f32_16x16x32_bf16(af1, bf1, acc[1][1], 0, 0, 0);
    }
    // transpose via LDS (reuse As) -> coalesced qt[bg][i][ch] bf16 stores
    __syncthreads();
#pragma unroll
    for (int im = 0; im < 2; im++)
#pragma unroll
        for (int r = 0; r < 4; r++) {
            int m = wm + im * 16 + quad * 4 + r;
#pragma unroll
            for (int in_ = 0; in_ < 2; in_++) {
                int n = wn + in_ * 16 + l15;
                As[n][m] = f2bf(acc[im][in_][r]);
            }
        }
    __syncthreads();
    {
        int n = tid >> 2;
        int c0 = (tid & 3) * 16;
        short8 a = *(const short8*)&As[n][c0];
        short8 c = *(const short8*)&As[n][c0 + 8];
        unsigned short* dst = qt + ((size_t)bg * 1024 + i0 + n) * 64 + c0;
        *(short8*)dst = a;
        *(short8*)(dst + 8) = c;
    }
}

// ---------------- K3+K4+K5 fused: offsets -> vgrid -> grid_sample(BN1) -> k/v conv (r11 shape) ----------------
__global__ __launch_bounds__(64) void k_offskv(
    const unsigned short* __restrict__ qt, const float* __restrict__ dww,
    const float* __restrict__ dwb, const float* __restrict__ pw,
    const float* __restrict__ x, const float* __restrict__ g1,
    const float* __restrict__ b1, const float* __restrict__ kw,
    const float* __restrict__ vw, float* __restrict__ vgrid,
    float* __restrict__ kk, float* __restrict__ vv) {
    __shared__ float sm[64];
    int blk = blockIdx.x;
    int bg = blk >> 6;
    int hd = (blk >> 3) & 7;
    int wd = blk & 7;
    int g = bg & 7, b = bg >> 3;
    int ch = threadIdx.x;
    const unsigned short* qb = qt + (size_t)bg * 65536;
    float acc = 0.f;
#pragma unroll
    for (int kh = 0; kh < 6; kh++) {
        int hin = hd * 4 - 1 + kh;
        if (hin < 0 || hin >= HH) continue;
#pragma unroll
        for (int kw_ = 0; kw_ < 6; kw_++) {
            int win = wd * 4 - 1 + kw_;
            if (win < 0 || win >= WW) continue;
            acc = fmaf(bf2f(qb[(hin * WW + win) * 64 + ch]), dww[ch * 36 + kh * 6 + kw_], acc);
        }
    }
    acc += dwb[ch];
    float ge = 0.5f * acc * (1.0f + erff(acc * 0.7071067811865475f));
    float p0 = ge * pw[ch];
    float p1 = ge * pw[64 + ch];
#pragma unroll
    for (int off = 32; off; off >>= 1) {
        p0 += __shfl_xor(p0, off);
        p1 += __shfl_xor(p1, off);
    }
    float nx = 2.0f * ((float)wd + tanhf(p0) * 4.0f) / 7.0f - 1.0f;
    float ny = 2.0f * ((float)hd + tanhf(p1) * 4.0f) / 7.0f - 1.0f;
    if (ch == 0) {
        vgrid[blk * 2] = nx;
        vgrid[blk * 2 + 1] = ny;
    }
    {
        int cg = g * 64 + ch;
        const float invs = 1.0f / sqrtf(1.0f + EPS);
        float s = g1[cg] * invs;
        float bv = b1[cg];
        float gx = (nx + 1.0f) * 16.0f - 0.5f;
        float gy = (ny + 1.0f) * 16.0f - 0.5f;
        float x0f = floorf(gx), y0f = floorf(gy);
        float wx = gx - x0f, wy = gy - y0f;
        int x0 = (int)x0f, y0 = (int)y0f;
        const float* im = x + (size_t)(b * CC + cg) * HWP;
        float sx = 0.f, sw = 0.f;
        float w00 = (1 - wx) * (1 - wy), w01 = wx * (1 - wy);
        float w10 = (1 - wx) * wy, w11 = wx * wy;
        if (x0 >= 0 && x0 < WW && y0 >= 0 && y0 < HH)                 { sx += w00 * im[y0 * WW + x0];           sw += w00; }
        if (x0 + 1 >= 0 && x0 + 1 < WW && y0 >= 0 && y0 < HH)         { sx += w01 * im[y0 * WW + x0 + 1];       sw += w01; }
        if (x0 >= 0 && x0 < WW && y0 + 1 >= 0 && y0 + 1 < HH)         { sx += w10 * im[(y0 + 1) * WW + x0];     sw += w10; }
        if (x0 + 1 >= 0 && x0 + 1 < WW && y0 + 1 >= 0 && y0 + 1 < HH) { sx += w11 * im[(y0 + 1) * WW + x0 + 1]; sw += w11; }
        sm[ch] = s * sx + bv * sw;
    }
    __syncthreads();
    int j = blk & 63;
    const float* kwr = kw + (size_t)(g * 64 + ch) * 64;
    const float* vwr = vw + (size_t)(g * 64 + ch) * 64;
    float ak = 0.f, av = 0.f;
#pragma unroll
    for (int c = 0; c < 64; c++) {
        float tv = sm[c];
        ak = fmaf(tv, kwr[c], ak);
        av = fmaf(tv, vwr[c], av);
    }
    kk[(size_t)bg * 4096 + j * 64 + ch] = ak;
    vv[(size_t)bg * 4096 + j * 64 + ch] = av;
}

// ---------------- K6: CPB bias MLP via bf16 MFMA (v6, bf16 bias out; frozen ~79us) ----------------
__global__ __launch_bounds__(256) void k_cpb(
    const float* __restrict__ vgrid, const unsigned short* __restrict__ w2p,
    const float* __restrict__ w1, const float* __restrict__ b1,
    const float* __restrict__ b2, const float* __restrict__ w3,
    const float* __restrict__ b3, unsigned short* __restrict__ bias) {
    __shared__ __align__(16) short w2fs[16384];   // exactly 32768 B -> 5 blocks/CU
    int tid = threadIdx.x;
    {
        const u32x4* src = (const u32x4*)w2p;
        u32x4* dst = (u32x4*)w2fs;
        for (int c = tid; c < 2048; c += 256) dst[c] = src[c];
    }
    float bias3 = b3[0];
    __syncthreads();

    int lane = tid & 63;
    int wv = tid >> 6;
    int l15 = lane & 15;
    int quad = lane >> 4;

#pragma unroll 1
    for (int it = 0; it < 4; it++) {
        int p = (blockIdx.x * 4 + it) * 4 + wv;
        int cofs = (int)((unsigned)p >> 20);   // runtime 0, compiler-opaque (anti-LICM)
        int bg = p >> 11;
        int i = (p >> 1) & 1023;
        int jbase = (p & 1) * 32;
        int hi = i >> 5, wi = i & 31;
        float qx = 2.0f * (float)wi / 31.0f - 1.0f;
        float qy = 2.0f * (float)hi / 31.0f - 1.0f;

        int jA = jbase + l15;
        float gkxA = vgrid[(bg * 64 + jA) * 2];
        float gkyA = vgrid[(bg * 64 + jA) * 2 + 1];
        float gkxB = vgrid[(bg * 64 + jA + 16) * 2];
        float gkyB = vgrid[(bg * 64 + jA + 16) * 2 + 1];
        float p0 = qx - gkxA, p1 = qy - gkyA;
        float s0a = copysignf(log1pf(fabsf(p0)), p0);
        float s1a = copysignf(log1pf(fabsf(p1)), p1);
        p0 = qx - gkxB; p1 = qy - gkyB;
        float s0b = copysignf(log1pf(fabsf(p0)), p0);
        float s1b = copysignf(log1pf(fabsf(p1)), p1);

        short8 hA[4], hB[4];
#pragma unroll
        for (int kc = 0; kc < 4; kc++) {
            f32x4 cu0 = *(const f32x4*)(w1 + cofs + kc * 32 + quad * 8);
            f32x4 cu1 = *(const f32x4*)(w1 + cofs + kc * 32 + quad * 8 + 4);
            f32x4 cv0 = *(const f32x4*)(w1 + cofs + 128 + kc * 32 + quad * 8);
            f32x4 cv1 = *(const f32x4*)(w1 + cofs + 128 + kc * 32 + quad * 8 + 4);
            f32x4 cb0 = *(const f32x4*)(b1 + cofs + kc * 32 + quad * 8);
            f32x4 cb1 = *(const f32x4*)(b1 + cofs + kc * 32 + quad * 8 + 4);
            u32x4 pa, pb;
#pragma unroll
            for (int j2 = 0; j2 < 4; j2++) {
                int e0 = 2 * j2, e1 = 2 * j2 + 1;
                float u0 = (e0 < 4) ? cu0[e0] : cu1[e0 - 4];
                float u1 = (e1 < 4) ? cu0[e1] : cu1[e1 - 4];
                float v0 = (e0 < 4) ? cv0[e0] : cv1[e0 - 4];
                float v1 = (e1 < 4) ? cv0[e1] : cv1[e1 - 4];
                float c0 = (e0 < 4) ? cb0[e0] : cb1[e0 - 4];
                float c1 = (e1 < 4) ? cb0[e1] : cb1[e1 - 4];
                unsigned a0 = __builtin_bit_cast(unsigned,
                    fmaxf(fmaf(s0a, u0, fmaf(s1a, v0, c0)), 0.f)) + 0x8000u;
                unsigned a1 = __builtin_bit_cast(unsigned,
                    fmaxf(fmaf(s0a, u1, fmaf(s1a, v1, c1)), 0.f)) + 0x8000u;
                pa[j2] = __builtin_amdgcn_perm(a1, a0, 0x07060302);
                unsigned b0 = __builtin_bit_cast(unsigned,
                    fmaxf(fmaf(s0b, u0, fmaf(s1b, v0, c0)), 0.f)) + 0x8000u;
                unsigned b1_ = __builtin_bit_cast(unsigned,
                    fmaxf(fmaf(s0b, u1, fmaf(s1b, v1, c1)), 0.f)) + 0x8000u;
                pb[j2] = __builtin_amdgcn_perm(b1_, b0, 0x07060302);
            }
            hA[kc] = __builtin_bit_cast(short8, pa);
            hB[kc] = __builtin_bit_cast(short8, pb);
        }

        float psumA = 0.f, psumB = 0.f;
#pragma unroll 2
        for (int nt = 0; nt < 8; nt++) {
            f32x4 accA = (f32x4){0.f, 0.f, 0.f, 0.f};
            f32x4 accB = (f32x4){0.f, 0.f, 0.f, 0.f};
#pragma unroll
            for (int kc = 0; kc < 4; kc++) {
                short8 af = *(const short8*)(w2fs + (((nt * 4 + kc) * 64) + lane) * 8);
                accA = __builtin_amdgcn_mfma_f32_16x16x32_bf16(af, hA[kc], accA, 0, 0, 0);
                accB = __builtin_amdgcn_mfma_f32_16x16x32_bf16(af, hB[kc], accB, 0, 0, 0);
            }
            f32x4 b2q = *(const f32x4*)(b2 + cofs + nt * 16 + quad * 4);
            f32x4 w3q = *(const f32x4*)(w3 + cofs + nt * 16 + quad * 4);
#pragma unroll
            for (int r = 0; r < 4; r++) {
                psumA = fmaf(fmaxf(accA[r] + b2q[r], 0.f), w3q[r], psumA);
                psumB = fmaf(fmaxf(accB[r] + b2q[r], 0.f), w3q[r], psumB);
            }
        }
        psumA += __shfl_xor(psumA, 16);
        psumA += __shfl_xor(psumA, 32);
        psumB += __shfl_xor(psumB, 16);
        psumB += __shfl_xor(psumB, 32);
        if (quad == 0) {
            bias[(size_t)(p * 2 + 0) * 16 + l15] = (unsigned short)f2bf(psumA + bias3);
            bias[(size_t)(p * 2 + 1) * 16 + l15] = (unsigned short)f2bf(psumB + bias3);
        }
    }
}

// ---------------- K7: attention via MFMA (bf16 bias) ----------------
__global__ __launch_bounds__(256) void k_attn(
    const unsigned short* __restrict__ qt, const float* __restrict__ kk,
    const float* __restrict__ vv, const unsigned short* __restrict__ bias,
    unsigned short* __restrict__ ao) {
    __shared__ __align__(16) short Ks[64][72];
    __shared__ __align__(16) short Vt[64][72];
    __shared__ __align__(16) short Qs[64][72];
    __shared__ __align__(16) short Ps[4][16][72];
    int blk = blockIdx.x;
    int bg = blk >> 4;
    int chunk = blk & 15;
    int i0 = chunk * 64;
    int b = bg >> 3, g = bg & 7;
    int tid = threadIdx.x, lane = tid & 63, wv = tid >> 6;
    int l15 = lane & 15, quad = lane >> 4;

    const float* kbase = kk + (size_t)bg * 4096;
    const float* vbase = vv + (size_t)bg * 4096;
#pragma unroll
    for (int it = 0; it < 4; it++) {
        int e4 = it * 1024 + tid * 4;
        int j = e4 >> 6, d = e4 & 63;
        f32x4 k4 = *(const f32x4*)(kbase + e4);
        s16x4 s = {f2bf(k4.x), f2bf(k4.y), f2bf(k4.z), f2bf(k4.w)};
        *(s16x4*)&Ks[j][d] = s;
        f32x4 v4 = *(const f32x4*)(vbase + e4);
        Vt[d + 0][j] = f2bf(v4.x);
        Vt[d + 1][j] = f2bf(v4.y);
        Vt[d + 2][j] = f2bf(v4.z);
        Vt[d + 3][j] = f2bf(v4.w);
    }
    {
        const unsigned short* qtb = qt + ((size_t)bg * 1024 + i0) * 64;
#pragma unroll
        for (int it = 0; it < 4; it++) {
            int e4 = it * 1024 + tid * 4;
            int i = e4 >> 6, d = e4 & 63;
            u16x4 v = *(const u16x4*)(qtb + e4);
            *(u16x4*)&Qs[i][d] = v;
        }
    }
    __syncthreads();

    int iw = wv * 16;
    f32x4 Sacc[4];
#pragma unroll
    for (int nt = 0; nt < 4; nt++) Sacc[nt] = (f32x4){0.f, 0.f, 0.f, 0.f};
#pragma unroll
    for (int ks = 0; ks < 2; ks++) {
        short8 aq = *(const short8*)&Qs[iw + l15][quad * 8 + ks * 32];
#pragma unroll
        for (int nt = 0; nt < 4; nt++) {
            short8 bk = *(const short8*)&Ks[nt * 16 + l15][quad * 8 + ks * 32];
            Sacc[nt] = __builtin_amdgcn_mfma_f32_16x16x32_bf16(aq, bk, Sacc[nt], 0, 0, 0);
        }
    }
    const unsigned short* bp = bias + ((size_t)bg * 1024 + i0 + iw + quad * 4) * 64 + l15;
    float Sv[4][4];
#pragma unroll
    for (int nt = 0; nt < 4; nt++)
#pragma unroll
        for (int r = 0; r < 4; r++)
            Sv[nt][r] = fmaf(Sacc[nt][r], 0.125f, bf2f(bp[r * 64 + nt * 16]));
#pragma unroll
    for (int r = 0; r < 4; r++) {
        float m = fmaxf(fmaxf(Sv[0][r], Sv[1][r]), fmaxf(Sv[2][r], Sv[3][r]));
        m = fmaxf(m, __shfl_xor(m, 1));
        m = fmaxf(m, __shfl_xor(m, 2));
        m = fmaxf(m, __shfl_xor(m, 4));
        m = fmaxf(m, __shfl_xor(m, 8));
        float l = 0.f;
#pragma unroll
        for (int nt = 0; nt < 4; nt++) { Sv[nt][r] = expf(Sv[nt][r] - m); l += Sv[nt][r]; }
        l += __shfl_xor(l, 1);
        l += __shfl_xor(l, 2);
        l += __shfl_xor(l, 4);
        l += __shfl_xor(l, 8);
        float inv = 1.0f / l;
#pragma unroll
        for (int nt = 0; nt < 4; nt++)
            Ps[wv][quad * 4 + r][nt * 16 + l15] = f2bf(Sv[nt][r] * inv);
    }
    f32x4 Oacc[4];
#pragma unroll
    for (int nt = 0; nt < 4; nt++) Oacc[nt] = (f32x4){0.f, 0.f, 0.f, 0.f};
#pragma unroll
    for (int ks = 0; ks < 2; ks++) {
        short8 ap = *(const short8*)&Ps[wv][l15][quad * 8 + ks * 32];
#pragma unroll
        for (int nt = 0; nt < 4; nt++) {
            short8 bv = *(const short8*)&Vt[nt * 16 + l15][quad * 8 + ks * 32];
            Oacc[nt] = __builtin_amdgcn_mfma_f32_16x16x32_bf16(ap, bv, Oacc[nt], 0, 0, 0);
        }
    }
    __syncthreads();
#pragma unroll
    for (int nt = 0; nt < 4; nt++) {
        s16x4 o4 = {f2bf(Oacc[nt][0]), f2bf(Oacc[nt][1]), f2bf(Oacc[nt][2]), f2bf(Oacc[nt][3])};
        *(s16x4*)&Qs[nt * 16 + l15][iw + quad * 4] = o4;
    }
    __syncthreads();
    {
        int d = tid >> 2;
        int ic = (tid & 3) * 16;
        short8 a = *(const short8*)&Qs[d][ic];
        short8 c = *(const short8*)&Qs[d][ic + 8];
        unsigned short* dst = ao + (size_t)(b * CC + g * 64 + d) * HWP + i0 + ic;
        *(short8*)dst = a;
        *(short8*)(dst + 8) = c;
    }
}

// ---------------- K8/K10/K11: tiled bf16-MFMA GEMM, software-pipelined ----------------
// Prefetch next K-tile into registers while MFMAing current tile (grid is only
// 1 block/CU for the 256-block instances — no co-resident blocks to hide latency).
// EPI 0/2: +resid fp32. EPI 1: gelu bf16. EPI 3: +resid fp32 AND bf16(BN2) to out2.
template<int EPI, int KD, int BK, int MT>
__global__ __launch_bounds__(256) void k_gemm(
    const unsigned short* __restrict__ A, const unsigned short* __restrict__ Bh,
    const float* __restrict__ resid, const float* __restrict__ bias,
    void* __restrict__ outp, unsigned short* __restrict__ out2,
    const float* __restrict__ bns, const float* __restrict__ bnb) {
    constexpr int MM = MT * 64;
    constexpr int KV4 = BK / 4;        // u16x4 chunks per A row
    constexpr int RP = 256 / KV4;      // A rows per pass
    constexpr int NA = 64 / RP;        // A loads per thread
    constexpr int NB = BK / 16;        // B loads per thread
    __shared__ __align__(16) short As[64][BK + 8];
    __shared__ __align__(16) short Bs[64][BK + 8];
    int tid = threadIdx.x;
    int blk = blockIdx.x;
    int mt = blk & (MT - 1);
    int nb = blk / MT;              // 0..31
    int bb = nb >> 4, nt = nb & 15;
    int m0 = mt * 64, i0 = nt * 64;
    int lane = tid & 63, wv = tid >> 6;
    int wm = (wv >> 1) * 32, wn = (wv & 1) * 32;
    int l15 = lane & 15, quad = lane >> 4;
    const unsigned short* Af = A + (size_t)m0 * KD;
    const float invs = 1.0f / sqrtf(1.0f + EPS);
    int kk4 = (tid & (KV4 - 1)) * 4;
    int myb = tid / KV4;
    int i4 = (tid & 15) * 4;
    int kyb = tid >> 4;

    f32x4 acc[2][2];
#pragma unroll
    for (int a = 0; a < 2; a++)
#pragma unroll
        for (int c = 0; c < 2; c++) acc[a][c] = (f32x4){0.f, 0.f, 0.f, 0.f};

    u16x4 ra[NA], rb[NB];
    // prologue: load tile 0
#pragma unroll
    for (int p = 0; p < NA; p++)
        ra[p] = *(const u16x4*)(Af + (size_t)(myb + p * RP) * KD + kk4);
#pragma unroll
    for (int p = 0; p < NB; p++)
        rb[p] = *(const u16x4*)(Bh + (size_t)bb * KD * HWP + (size_t)(kyb + p * 16) * HWP + i0 + i4);

    for (int k0 = 0; k0 < KD; k0 += BK) {
        __syncthreads();   // all waves done reading LDS of previous tile
#pragma unroll
        for (int p = 0; p < NA; p++)
            *(u16x4*)&As[myb + p * RP][kk4] = ra[p];
#pragma unroll
        for (int p = 0; p < NB; p++) {
            int ky = kyb + p * 16;
            Bs[i4 + 0][ky] = (short)rb[p].x;
            Bs[i4 + 1][ky] = (short)rb[p].y;
            Bs[i4 + 2][ky] = (short)rb[p].z;
            Bs[i4 + 3][ky] = (short)rb[p].w;
        }
        __syncthreads();
        // prefetch next tile — loads in flight during the MFMA block below
        int kn = k0 + BK;
        if (kn < KD) {
#pragma unroll
            for (int p = 0; p < NA; p++)
                ra[p] = *(const u16x4*)(Af + (size_t)(myb + p * RP) * KD + kn + kk4);
#pragma unroll
            for (int p = 0; p < NB; p++)
                rb[p] = *(const u16x4*)(Bh + (size_t)bb * KD * HWP + (size_t)(kn + kyb + p * 16) * HWP + i0 + i4);
        }
#pragma unroll
        for (int ks = 0; ks < BK / 32; ks++) {
            short8 af0 = *(const short8*)&As[wm + l15][ks * 32 + quad * 8];
            short8 af1 = *(const short8*)&As[wm + 16 + l15][ks * 32 + quad * 8];
            short8 bf0 = *(const short8*)&Bs[wn + l15][ks * 32 + quad * 8];
            short8 bf1 = *(const short8*)&Bs[wn + 16 + l15][ks * 32 + quad * 8];
            acc[0][0] = __builtin_amdgcn_mfma_f32_16x16x32_bf16(af0, bf0, acc[0][0], 0, 0, 0);
            acc[0][1] = __builtin_amdgcn_mfma_f32_16x16x32_bf16(af0, bf1, acc[0][1], 0, 0, 0);
            acc[1][0] = __builtin_amdgcn_mfma_f32_16x16x32_bf16(af1, bf0, acc[1][0], 0, 0, 0);
            acc[1][1] = __builtin_amdgcn_mfma_f32_16x16x32_bf16(af1, bf1, acc[1][1], 0, 0, 0);
        }
    }

    float* outF = (float*)outp;
    unsigned short* outH = (unsigned short*)outp;
#pragma unroll
    for (int im = 0; im < 2; im++) {
#pragma unroll
        for (int r = 0; r < 4; r++) {
            int m = m0 + wm + im * 16 + quad * 4 + r;
            float bv = bias[m];
#pragma unroll
            for (int in_ = 0; in_ < 2; in_++) {
                int n = i0 + wn + in_ * 16 + l15;
                size_t idx = ((size_t)bb * MM + m) * HWP + n;
                float v = acc[im][in_][r] + bv;
                if constexpr (EPI == 1) {
                    float ge = 0.5f * v * (1.0f + erff(v * 0.7071067811865475f));
                    outH[idx] = (unsigned short)f2bf(ge);
                } else if constexpr (EPI == 3) {
                    float vr = v + resid[idx];
                    outF[idx] = vr;
                    out2[idx] = (unsigned short)f2bf(fmaf(vr, bns[m] * invs, bnb[m]));
                } else {
                    outF[idx] = v + resid[idx];
                }
            }
        }
    }
}

extern "C" void kernel_launch(void* const* d_in, const int* in_sizes, int n_in,
                              void* d_out, int out_size, void* d_ws, size_t ws_size,
                              hipStream_t stream) {
    const float* x      = (const float*)d_in[0];
    const float* bn1_g  = (const float*)d_in[1];
    const float* bn1_b  = (const float*)d_in[2];
    const float* bn2_g  = (const float*)d_in[3];
    const float* bn2_b  = (const float*)d_in[4];
    const float* qw     = (const float*)d_in[5];
    const float* kw     = (const float*)d_in[6];
    const float* vw     = (const float*)d_in[7];
    const float* out_w  = (const float*)d_in[8];
    const float* out_b  = (const float*)d_in[9];
    const float* off_dw_w = (const float*)d_in[10];
    const float* off_dw_b = (const float*)d_in[11];
    const float* off_pw_w = (const float*)d_in[12];
    const float* cpb_w1 = (const float*)d_in[13];
    const float* cpb_b1 = (const float*)d_in[14];
    const float* cpb_w2 = (const float*)d_in[15];
    const float* cpb_b2 = (const float*)d_in[16];
    const float* cpb_w3 = (const float*)d_in[17];
    const float* cpb_b3 = (const float*)d_in[18];
    const float* mlp_w1 = (const float*)d_in[19];
    const float* mlp_b1 = (const float*)d_in[20];
    const float* mlp_w2 = (const float*)d_in[21];
    const float* mlp_b2 = (const float*)d_in[22];

    float* ws = (float*)d_ws;
    unsigned short* qt = (unsigned short*)(ws + 1048576);   // 1,048,576 bf16
    float* vgrid = ws + 2097152;      // 2,048
    float* kk    = ws + 2164736;      // 65,536
    float* vv    = ws + 2230272;      // 65,536
    unsigned short* w2p = (unsigned short*)(ws + 2295808);  // 16,384 bf16
    unsigned short* ao  = (unsigned short*)(ws + 2312192);  // 1,048,576 bf16
    unsigned short* xn2 = (unsigned short*)(ws + 2836480);  // 1,048,576 bf16
    float* xo    = ws + 3360768;      // 1,048,576 floats
    float* h1of  = ws + 4409344;      // bias bf16 (1M ushorts), then h1o bf16 (4M ushorts)
    unsigned short* biasb = (unsigned short*)h1of;          // consumed by k_attn before g1 writes h1o
    unsigned short* h1o = (unsigned short*)h1of;
    unsigned short* wp  = (unsigned short*)(ws + 6506496);  // 2,392,064 ushorts
    unsigned short* qwp  = wp;
    unsigned short* owp  = wp + 32768;
    unsigned short* w1p  = wp + 294912;
    unsigned short* w2mp = wp + 1343488;

    hipLaunchKernelGGL(k_wpack, dim3(9408), dim3(256), 0, stream,
                       qw, out_w, mlp_w1, mlp_w2, cpb_w2, wp, w2p);
    hipLaunchKernelGGL(k_qgemm, dim3(256), dim3(256), 0, stream, x, bn1_g, bn1_b, qwp, qt);
    hipLaunchKernelGGL(k_offskv, dim3(1024), dim3(64), 0, stream,
                       qt, off_dw_w, off_dw_b, off_pw_w, x, bn1_g, bn1_b, kw, vw,
                       vgrid, kk, vv);
    hipLaunchKernelGGL(k_cpb, dim3(2048), dim3(256), 0, stream,
                       vgrid, w2p, cpb_w1, cpb_b1, cpb_b2, cpb_w3, cpb_b3, biasb);
    hipLaunchKernelGGL(k_attn, dim3(256), dim3(256), 0, stream, qt, kk, vv, biasb, ao);
    // out projection: M=512, K=512 (BK=128), B=ao bf16, resid=x -> xo + xn2(BN2 bf16)
    k_gemm<3, 512, 128, 8><<<dim3(256), dim3(256), 0, stream>>>(
        owp, ao, x, out_b, xo, xn2, bn2_g, bn2_b);
    // MLP1: M=2048, K=512 (BK=128), B=xn2 bf16, gelu -> h1o bf16
    k_gemm<1, 512, 128, 32><<<dim3(1024), dim3(256), 0, stream>>>(
        w1p, xn2, nullptr, mlp_b1, h1o, nullptr, nullptr, nullptr);
    // MLP2: M=512, K=2048 (BK=128), B=h1o bf16, resid=xo -> d_out
    k_gemm<2, 2048, 128, 8><<<dim3(256), dim3(256), 0, stream>>>(
        w2mp, h1o, xo, mlp_b2, d_out, nullptr, nullptr, nullptr);
}

// Round 14
// 239.497 us; speedup vs baseline: 1.1282x; 1.0674x over previous
//
#include <hip/hip_runtime.h>
#include <hip/hip_bf16.h>
#include <math.h>

// Problem constants
#define BB 2
#define CC 512
#define HH 32
#define WW 32
#define HWP 1024      // H*W
#define GG 8
#define DH 64
#define HD 8
#define WD 8
#define JJ 64         // HD*WD
#define BG 16         // BB*GG
#define EPS 1e-5f

typedef __attribute__((ext_vector_type(8))) short short8;
typedef __attribute__((ext_vector_type(4))) short s16x4;
typedef __attribute__((ext_vector_type(4))) float f32x4;
typedef __attribute__((ext_vector_type(4))) unsigned short u16x4;
typedef __attribute__((ext_vector_type(4))) unsigned int u32x4;

// RNE float -> bf16 bits
static __device__ __forceinline__ short f2bf(float x) {
    unsigned u = __builtin_bit_cast(unsigned, x);
    u += 0x7FFFu + ((u >> 16) & 1u);
    return (short)(u >> 16);
}
static __device__ __forceinline__ float bf2f(unsigned short h) {
    return __builtin_bit_cast(float, (unsigned)h << 16);
}

// ---------------- K0: pre-pack ALL weights to bf16 ----------------
__global__ void k_wpack(const float* __restrict__ qw, const float* __restrict__ ow,
                        const float* __restrict__ w1, const float* __restrict__ w2,
                        const float* __restrict__ cw2, unsigned short* __restrict__ wp,
                        unsigned short* __restrict__ w2p) {
    int idx = blockIdx.x * 256 + threadIdx.x;
    if (idx < 2392064) {
        float v;
        if (idx < 32768) v = qw[idx];
        else if (idx < 294912) v = ow[idx - 32768];
        else if (idx < 1343488) v = w1[idx - 294912];
        else v = w2[idx - 1343488];
        wp[idx] = (unsigned short)f2bf(v);
    } else if (idx < 2408448) {
        int i2 = idx - 2392064;
        int k = i2 >> 7, n = i2 & 127;
        int dest = ((((n >> 4) * 4 + (k >> 5)) * 64) + (((k >> 3) & 3) * 16) + (n & 15)) * 8 + (k & 7);
        w2p[dest] = (unsigned short)f2bf(cw2[i2]);
    }
}

// ---------------- K2: q grouped 1x1 conv via MFMA -> qt[bg][i][ch] bf16 ----------------
__global__ __launch_bounds__(256) void k_qgemm(
    const float* __restrict__ x, const float* __restrict__ g1,
    const float* __restrict__ b1, const unsigned short* __restrict__ qwp,
    unsigned short* __restrict__ qt) {
    __shared__ __align__(16) short As[64][72];
    __shared__ __align__(16) short Bs[64][72];
    int blk = blockIdx.x;
    int bg = blk >> 4, nt = blk & 15;
    int b = bg >> 3, g = bg & 7;
    int i0 = nt * 64;
    int tid = threadIdx.x, lane = tid & 63, wv = tid >> 6;
    int wm = (wv >> 1) * 32, wn = (wv & 1) * 32;
    int l15 = lane & 15, quad = lane >> 4;
    const float invs = 1.0f / sqrtf(1.0f + EPS);
    {
        int c4 = (tid & 15) * 4;
        int ob = tid >> 4;
#pragma unroll
        for (int p = 0; p < 4; p++) {
            int o = ob + p * 16;
            u16x4 v = *(const u16x4*)(qwp + (size_t)(g * 64 + o) * 64 + c4);
            *(u16x4*)&As[o][c4] = v;
        }
    }
    {
        int i4 = (tid & 15) * 4;
        int cb = tid >> 4;
#pragma unroll
        for (int p = 0; p < 4; p++) {
            int c = cb + p * 16;
            f32x4 v = *(const f32x4*)(x + (size_t)(b * CC + g * 64 + c) * HWP + i0 + i4);
            float sc = g1[g * 64 + c] * invs;
            float sh = b1[g * 64 + c];
            Bs[i4 + 0][c] = f2bf(fmaf(v.x, sc, sh));
            Bs[i4 + 1][c] = f2bf(fmaf(v.y, sc, sh));
            Bs[i4 + 2][c] = f2bf(fmaf(v.z, sc, sh));
            Bs[i4 + 3][c] = f2bf(fmaf(v.w, sc, sh));
        }
    }
    __syncthreads();
    f32x4 acc[2][2];
#pragma unroll
    for (int a = 0; a < 2; a++)
#pragma unroll
        for (int c = 0; c < 2; c++) acc[a][c] = (f32x4){0.f, 0.f, 0.f, 0.f};
#pragma unroll
    for (int ks = 0; ks < 2; ks++) {
        short8 af0 = *(const short8*)&As[wm + l15][ks * 32 + quad * 8];
        short8 af1 = *(const short8*)&As[wm + 16 + l15][ks * 32 + quad * 8];
        short8 bf0 = *(const short8*)&Bs[wn + l15][ks * 32 + quad * 8];
        short8 bf1 = *(const short8*)&Bs[wn + 16 + l15][ks * 32 + quad * 8];
        acc[0][0] = __builtin_amdgcn_mfma_f32_16x16x32_bf16(af0, bf0, acc[0][0], 0, 0, 0);
        acc[0][1] = __builtin_amdgcn_mfma_f32_16x16x32_bf16(af0, bf1, acc[0][1], 0, 0, 0);
        acc[1][0] = __builtin_amdgcn_mfma_f32_16x16x32_bf16(af1, bf0, acc[1][0], 0, 0, 0);
        acc[1][1] = __builtin_amdgcn_mfma_f32_16x16x32_bf16(af1, bf1, acc[1][1], 0, 0, 0);
    }
    // transpose via LDS (reuse As) -> coalesced qt[bg][i][ch] bf16 stores
    __syncthreads();
#pragma unroll
    for (int im = 0; im < 2; im++)
#pragma unroll
        for (int r = 0; r < 4; r++) {
            int m = wm + im * 16 + quad * 4 + r;
#pragma unroll
            for (int in_ = 0; in_ < 2; in_++) {
                int n = wn + in_ * 16 + l15;
                As[n][m] = f2bf(acc[im][in_][r]);
            }
        }
    __syncthreads();
    {
        int n = tid >> 2;
        int c0 = (tid & 3) * 16;
        short8 a = *(const short8*)&As[n][c0];
        short8 c = *(const short8*)&As[n][c0 + 8];
        unsigned short* dst = qt + ((size_t)bg * 1024 + i0 + n) * 64 + c0;
        *(short8*)dst = a;
        *(short8*)(dst + 8) = c;
    }
}

// ---------------- K3+K4+K5 fused: offsets -> vgrid -> grid_sample(BN1) -> k/v conv ----------------
__global__ __launch_bounds__(64) void k_offskv(
    const unsigned short* __restrict__ qt, const float* __restrict__ dww,
    const float* __restrict__ dwb, const float* __restrict__ pw,
    const float* __restrict__ x, const float* __restrict__ g1,
    const float* __restrict__ b1, const float* __restrict__ kw,
    const float* __restrict__ vw, float* __restrict__ vgrid,
    float* __restrict__ kk, float* __restrict__ vv) {
    __shared__ float sm[64];
    int blk = blockIdx.x;
    int bg = blk >> 6;
    int hd = (blk >> 3) & 7;
    int wd = blk & 7;
    int g = bg & 7, b = bg >> 3;
    int ch = threadIdx.x;
    const unsigned short* qb = qt + (size_t)bg * 65536;
    float acc = 0.f;
#pragma unroll
    for (int kh = 0; kh < 6; kh++) {
        int hin = hd * 4 - 1 + kh;
        if (hin < 0 || hin >= HH) continue;
#pragma unroll
        for (int kw_ = 0; kw_ < 6; kw_++) {
            int win = wd * 4 - 1 + kw_;
            if (win < 0 || win >= WW) continue;
            acc = fmaf(bf2f(qb[(hin * WW + win) * 64 + ch]), dww[ch * 36 + kh * 6 + kw_], acc);
        }
    }
    acc += dwb[ch];
    float ge = 0.5f * acc * (1.0f + erff(acc * 0.7071067811865475f));
    float p0 = ge * pw[ch];
    float p1 = ge * pw[64 + ch];
#pragma unroll
    for (int off = 32; off; off >>= 1) {
        p0 += __shfl_xor(p0, off);
        p1 += __shfl_xor(p1, off);
    }
    float nx = 2.0f * ((float)wd + tanhf(p0) * 4.0f) / 7.0f - 1.0f;
    float ny = 2.0f * ((float)hd + tanhf(p1) * 4.0f) / 7.0f - 1.0f;
    if (ch == 0) {
        vgrid[blk * 2] = nx;
        vgrid[blk * 2 + 1] = ny;
    }
    {
        int cg = g * 64 + ch;
        const float invs = 1.0f / sqrtf(1.0f + EPS);
        float s = g1[cg] * invs;
        float bv = b1[cg];
        float gx = (nx + 1.0f) * 16.0f - 0.5f;
        float gy = (ny + 1.0f) * 16.0f - 0.5f;
        float x0f = floorf(gx), y0f = floorf(gy);
        float wx = gx - x0f, wy = gy - y0f;
        int x0 = (int)x0f, y0 = (int)y0f;
        const float* im = x + (size_t)(b * CC + cg) * HWP;
        float sx = 0.f, sw = 0.f;
        float w00 = (1 - wx) * (1 - wy), w01 = wx * (1 - wy);
        float w10 = (1 - wx) * wy, w11 = wx * wy;
        if (x0 >= 0 && x0 < WW && y0 >= 0 && y0 < HH)                 { sx += w00 * im[y0 * WW + x0];           sw += w00; }
        if (x0 + 1 >= 0 && x0 + 1 < WW && y0 >= 0 && y0 < HH)         { sx += w01 * im[y0 * WW + x0 + 1];       sw += w01; }
        if (x0 >= 0 && x0 < WW && y0 + 1 >= 0 && y0 + 1 < HH)         { sx += w10 * im[(y0 + 1) * WW + x0];     sw += w10; }
        if (x0 + 1 >= 0 && x0 + 1 < WW && y0 + 1 >= 0 && y0 + 1 < HH) { sx += w11 * im[(y0 + 1) * WW + x0 + 1]; sw += w11; }
        sm[ch] = s * sx + bv * sw;
    }
    __syncthreads();
    int j = blk & 63;
    const float* kwr = kw + (size_t)(g * 64 + ch) * 64;
    const float* vwr = vw + (size_t)(g * 64 + ch) * 64;
    float ak = 0.f, av = 0.f;
#pragma unroll
    for (int c = 0; c < 64; c++) {
        float tv = sm[c];
        ak = fmaf(tv, kwr[c], ak);
        av = fmaf(tv, vwr[c], av);
    }
    kk[(size_t)bg * 4096 + j * 64 + ch] = ak;
    vv[(size_t)bg * 4096 + j * 64 + ch] = av;
}

// ---------------- K6: CPB bias MLP via bf16 MFMA (v7: scalarized uniform loads) ----------------
// pu = readfirstlane(p): provably wave-uniform -> coef bases become scalar
// (s_load path, no per-lane address VALU). cofs stays compiler-opaque-zero
// to block full LICM hoisting of 24 f32x4 into ~96 VGPRs (r4 lesson).
__global__ __launch_bounds__(256) void k_cpb(
    const float* __restrict__ vgrid, const unsigned short* __restrict__ w2p,
    const float* __restrict__ w1, const float* __restrict__ b1,
    const float* __restrict__ b2, const float* __restrict__ w3,
    const float* __restrict__ b3, unsigned short* __restrict__ bias) {
    __shared__ __align__(16) short w2fs[16384];   // exactly 32768 B -> 5 blocks/CU
    int tid = threadIdx.x;
    {
        const u32x4* src = (const u32x4*)w2p;
        u32x4* dst = (u32x4*)w2fs;
        for (int c = tid; c < 2048; c += 256) dst[c] = src[c];
    }
    float bias3 = b3[0];
    __syncthreads();

    int lane = tid & 63;
    int wv = tid >> 6;
    int l15 = lane & 15;
    int quad = lane >> 4;

#pragma unroll 1
    for (int it = 0; it < 4; it++) {
        int p = (blockIdx.x * 4 + it) * 4 + wv;
        int pu = __builtin_amdgcn_readfirstlane(p);      // wave-uniform -> SGPR
        int cofs = (int)((unsigned)pu >> 20);            // runtime 0, opaque, scalar
        int bg = p >> 11;
        int i = (p >> 1) & 1023;
        int jbase = (p & 1) * 32;
        int hi = i >> 5, wi = i & 31;
        float qx = 2.0f * (float)wi / 31.0f - 1.0f;
        float qy = 2.0f * (float)hi / 31.0f - 1.0f;

        int jA = jbase + l15;
        float gkxA = vgrid[(bg * 64 + jA) * 2];
        float gkyA = vgrid[(bg * 64 + jA) * 2 + 1];
        float gkxB = vgrid[(bg * 64 + jA + 16) * 2];
        float gkyB = vgrid[(bg * 64 + jA + 16) * 2 + 1];
        float p0 = qx - gkxA, p1 = qy - gkyA;
        float s0a = copysignf(log1pf(fabsf(p0)), p0);
        float s1a = copysignf(log1pf(fabsf(p1)), p1);
        p0 = qx - gkxB; p1 = qy - gkyB;
        float s0b = copysignf(log1pf(fabsf(p0)), p0);
        float s1b = copysignf(log1pf(fabsf(p1)), p1);

        short8 hA[4], hB[4];
#pragma unroll
        for (int kc = 0; kc < 4; kc++) {
            f32x4 cu0 = *(const f32x4*)(w1 + cofs + kc * 32 + quad * 8);
            f32x4 cu1 = *(const f32x4*)(w1 + cofs + kc * 32 + quad * 8 + 4);
            f32x4 cv0 = *(const f32x4*)(w1 + cofs + 128 + kc * 32 + quad * 8);
            f32x4 cv1 = *(const f32x4*)(w1 + cofs + 128 + kc * 32 + quad * 8 + 4);
            f32x4 cb0 = *(const f32x4*)(b1 + cofs + kc * 32 + quad * 8);
            f32x4 cb1 = *(const f32x4*)(b1 + cofs + kc * 32 + quad * 8 + 4);
            u32x4 pa, pb;
#pragma unroll
            for (int j2 = 0; j2 < 4; j2++) {
                int e0 = 2 * j2, e1 = 2 * j2 + 1;
                float u0 = (e0 < 4) ? cu0[e0] : cu1[e0 - 4];
                float u1 = (e1 < 4) ? cu0[e1] : cu1[e1 - 4];
                float v0 = (e0 < 4) ? cv0[e0] : cv1[e0 - 4];
                float v1 = (e1 < 4) ? cv0[e1] : cv1[e1 - 4];
                float c0 = (e0 < 4) ? cb0[e0] : cb1[e0 - 4];
                float c1 = (e1 < 4) ? cb0[e1] : cb1[e1 - 4];
                unsigned a0 = __builtin_bit_cast(unsigned,
                    fmaxf(fmaf(s0a, u0, fmaf(s1a, v0, c0)), 0.f)) + 0x8000u;
                unsigned a1 = __builtin_bit_cast(unsigned,
                    fmaxf(fmaf(s0a, u1, fmaf(s1a, v1, c1)), 0.f)) + 0x8000u;
                pa[j2] = __builtin_amdgcn_perm(a1, a0, 0x07060302);
                unsigned b0 = __builtin_bit_cast(unsigned,
                    fmaxf(fmaf(s0b, u0, fmaf(s1b, v0, c0)), 0.f)) + 0x8000u;
                unsigned b1_ = __builtin_bit_cast(unsigned,
                    fmaxf(fmaf(s0b, u1, fmaf(s1b, v1, c1)), 0.f)) + 0x8000u;
                pb[j2] = __builtin_amdgcn_perm(b1_, b0, 0x07060302);
            }
            hA[kc] = __builtin_bit_cast(short8, pa);
            hB[kc] = __builtin_bit_cast(short8, pb);
        }

        float psumA = 0.f, psumB = 0.f;
#pragma unroll 2
        for (int nt = 0; nt < 8; nt++) {
            f32x4 accA = (f32x4){0.f, 0.f, 0.f, 0.f};
            f32x4 accB = (f32x4){0.f, 0.f, 0.f, 0.f};
#pragma unroll
            for (int kc = 0; kc < 4; kc++) {
                short8 af = *(const short8*)(w2fs + (((nt * 4 + kc) * 64) + lane) * 8);
                accA = __builtin_amdgcn_mfma_f32_16x16x32_bf16(af, hA[kc], accA, 0, 0, 0);
                accB = __builtin_amdgcn_mfma_f32_16x16x32_bf16(af, hB[kc], accB, 0, 0, 0);
            }
            f32x4 b2q = *(const f32x4*)(b2 + cofs + nt * 16 + quad * 4);
            f32x4 w3q = *(const f32x4*)(w3 + cofs + nt * 16 + quad * 4);
#pragma unroll
            for (int r = 0; r < 4; r++) {
                psumA = fmaf(fmaxf(accA[r] + b2q[r], 0.f), w3q[r], psumA);
                psumB = fmaf(fmaxf(accB[r] + b2q[r], 0.f), w3q[r], psumB);
            }
        }
        psumA += __shfl_xor(psumA, 16);
        psumA += __shfl_xor(psumA, 32);
        psumB += __shfl_xor(psumB, 16);
        psumB += __shfl_xor(psumB, 32);
        if (quad == 0) {
            bias[(size_t)(p * 2 + 0) * 16 + l15] = (unsigned short)f2bf(psumA + bias3);
            bias[(size_t)(p * 2 + 1) * 16 + l15] = (unsigned short)f2bf(psumB + bias3);
        }
    }
}

// ---------------- K7: attention via MFMA (bf16 bias) ----------------
__global__ __launch_bounds__(256) void k_attn(
    const unsigned short* __restrict__ qt, const float* __restrict__ kk,
    const float* __restrict__ vv, const unsigned short* __restrict__ bias,
    unsigned short* __restrict__ ao) {
    __shared__ __align__(16) short Ks[64][72];
    __shared__ __align__(16) short Vt[64][72];
    __shared__ __align__(16) short Qs[64][72];
    __shared__ __align__(16) short Ps[4][16][72];
    int blk = blockIdx.x;
    int bg = blk >> 4;
    int chunk = blk & 15;
    int i0 = chunk * 64;
    int b = bg >> 3, g = bg & 7;
    int tid = threadIdx.x, lane = tid & 63, wv = tid >> 6;
    int l15 = lane & 15, quad = lane >> 4;

    const float* kbase = kk + (size_t)bg * 4096;
    const float* vbase = vv + (size_t)bg * 4096;
#pragma unroll
    for (int it = 0; it < 4; it++) {
        int e4 = it * 1024 + tid * 4;
        int j = e4 >> 6, d = e4 & 63;
        f32x4 k4 = *(const f32x4*)(kbase + e4);
        s16x4 s = {f2bf(k4.x), f2bf(k4.y), f2bf(k4.z), f2bf(k4.w)};
        *(s16x4*)&Ks[j][d] = s;
        f32x4 v4 = *(const f32x4*)(vbase + e4);
        Vt[d + 0][j] = f2bf(v4.x);
        Vt[d + 1][j] = f2bf(v4.y);
        Vt[d + 2][j] = f2bf(v4.z);
        Vt[d + 3][j] = f2bf(v4.w);
    }
    {
        const unsigned short* qtb = qt + ((size_t)bg * 1024 + i0) * 64;
#pragma unroll
        for (int it = 0; it < 4; it++) {
            int e4 = it * 1024 + tid * 4;
            int i = e4 >> 6, d = e4 & 63;
            u16x4 v = *(const u16x4*)(qtb + e4);
            *(u16x4*)&Qs[i][d] = v;
        }
    }
    __syncthreads();

    int iw = wv * 16;
    f32x4 Sacc[4];
#pragma unroll
    for (int nt = 0; nt < 4; nt++) Sacc[nt] = (f32x4){0.f, 0.f, 0.f, 0.f};
#pragma unroll
    for (int ks = 0; ks < 2; ks++) {
        short8 aq = *(const short8*)&Qs[iw + l15][quad * 8 + ks * 32];
#pragma unroll
        for (int nt = 0; nt < 4; nt++) {
            short8 bk = *(const short8*)&Ks[nt * 16 + l15][quad * 8 + ks * 32];
            Sacc[nt] = __builtin_amdgcn_mfma_f32_16x16x32_bf16(aq, bk, Sacc[nt], 0, 0, 0);
        }
    }
    const unsigned short* bp = bias + ((size_t)bg * 1024 + i0 + iw + quad * 4) * 64 + l15;
    float Sv[4][4];
#pragma unroll
    for (int nt = 0; nt < 4; nt++)
#pragma unroll
        for (int r = 0; r < 4; r++)
            Sv[nt][r] = fmaf(Sacc[nt][r], 0.125f, bf2f(bp[r * 64 + nt * 16]));
#pragma unroll
    for (int r = 0; r < 4; r++) {
        float m = fmaxf(fmaxf(Sv[0][r], Sv[1][r]), fmaxf(Sv[2][r], Sv[3][r]));
        m = fmaxf(m, __shfl_xor(m, 1));
        m = fmaxf(m, __shfl_xor(m, 2));
        m = fmaxf(m, __shfl_xor(m, 4));
        m = fmaxf(m, __shfl_xor(m, 8));
        float l = 0.f;
#pragma unroll
        for (int nt = 0; nt < 4; nt++) { Sv[nt][r] = expf(Sv[nt][r] - m); l += Sv[nt][r]; }
        l += __shfl_xor(l, 1);
        l += __shfl_xor(l, 2);
        l += __shfl_xor(l, 4);
        l += __shfl_xor(l, 8);
        float inv = 1.0f / l;
#pragma unroll
        for (int nt = 0; nt < 4; nt++)
            Ps[wv][quad * 4 + r][nt * 16 + l15] = f2bf(Sv[nt][r] * inv);
    }
    f32x4 Oacc[4];
#pragma unroll
    for (int nt = 0; nt < 4; nt++) Oacc[nt] = (f32x4){0.f, 0.f, 0.f, 0.f};
#pragma unroll
    for (int ks = 0; ks < 2; ks++) {
        short8 ap = *(const short8*)&Ps[wv][l15][quad * 8 + ks * 32];
#pragma unroll
        for (int nt = 0; nt < 4; nt++) {
            short8 bv = *(const short8*)&Vt[nt * 16 + l15][quad * 8 + ks * 32];
            Oacc[nt] = __builtin_amdgcn_mfma_f32_16x16x32_bf16(ap, bv, Oacc[nt], 0, 0, 0);
        }
    }
    __syncthreads();
#pragma unroll
    for (int nt = 0; nt < 4; nt++) {
        s16x4 o4 = {f2bf(Oacc[nt][0]), f2bf(Oacc[nt][1]), f2bf(Oacc[nt][2]), f2bf(Oacc[nt][3])};
        *(s16x4*)&Qs[nt * 16 + l15][iw + quad * 4] = o4;
    }
    __syncthreads();
    {
        int d = tid >> 2;
        int ic = (tid & 3) * 16;
        short8 a = *(const short8*)&Qs[d][ic];
        short8 c = *(const short8*)&Qs[d][ic + 8];
        unsigned short* dst = ao + (size_t)(b * CC + g * 64 + d) * HWP + i0 + ic;
        *(short8*)dst = a;
        *(short8*)(dst + 8) = c;
    }
}

// ---------------- K8/K10/K11: tiled bf16-MFMA GEMM, pipelined + perm-transpose B-staging ----------------
// B-staging v2: each thread loads an 8k x 4i block and transposes IN REGISTERS
// via v_perm -> 4 ds_write_b128 (was 32 ds_write_b16 scatter). Bit-exact.
// EPI 0/2: +resid fp32. EPI 1: gelu bf16. EPI 3: +resid fp32 AND bf16(BN2) to out2.
template<int EPI, int KD, int BK, int MT>
__global__ __launch_bounds__(256) void k_gemm(
    const unsigned short* __restrict__ A, const unsigned short* __restrict__ Bh,
    const float* __restrict__ resid, const float* __restrict__ bias,
    void* __restrict__ outp, unsigned short* __restrict__ out2,
    const float* __restrict__ bns, const float* __restrict__ bnb) {
    constexpr int MM = MT * 64;
    constexpr int KV4 = BK / 4;        // u16x4 chunks per A row
    constexpr int RP = 256 / KV4;      // A rows per pass
    constexpr int NA = 64 / RP;        // A loads per thread
    constexpr int NB = BK / 16;        // B k-rows per thread (consecutive)
    __shared__ __align__(16) short As[64][BK + 8];
    __shared__ __align__(16) short Bs[64][BK + 8];
    int tid = threadIdx.x;
    int blk = blockIdx.x;
    int mt = blk & (MT - 1);
    int nb = blk / MT;              // 0..31
    int bb = nb >> 4, nt = nb & 15;
    int m0 = mt * 64, i0 = nt * 64;
    int lane = tid & 63, wv = tid >> 6;
    int wm = (wv >> 1) * 32, wn = (wv & 1) * 32;
    int l15 = lane & 15, quad = lane >> 4;
    const unsigned short* Af = A + (size_t)m0 * KD;
    const float invs = 1.0f / sqrtf(1.0f + EPS);
    int kk4 = (tid & (KV4 - 1)) * 4;
    int myb = tid / KV4;
    int i4 = (tid & 15) * 4;
    int kyb8 = (tid >> 4) * NB;       // 8 consecutive k rows per thread

    f32x4 acc[2][2];
#pragma unroll
    for (int a = 0; a < 2; a++)
#pragma unroll
        for (int c = 0; c < 2; c++) acc[a][c] = (f32x4){0.f, 0.f, 0.f, 0.f};

    u16x4 ra[NA], rb[NB];
    // prologue: load tile 0
#pragma unroll
    for (int p = 0; p < NA; p++)
        ra[p] = *(const u16x4*)(Af + (size_t)(myb + p * RP) * KD + kk4);
#pragma unroll
    for (int p = 0; p < NB; p++)
        rb[p] = *(const u16x4*)(Bh + (size_t)bb * KD * HWP + (size_t)(kyb8 + p) * HWP + i0 + i4);

    for (int k0 = 0; k0 < KD; k0 += BK) {
        __syncthreads();   // all waves done reading LDS of previous tile
#pragma unroll
        for (int p = 0; p < NA; p++)
            *(u16x4*)&As[myb + p * RP][kk4] = ra[p];
        // in-register 8k x 4i transpose -> 4 b128 rows
#pragma unroll
        for (int q = 0; q < 4; q++) {
            u32x4 w;
#pragma unroll
            for (int j = 0; j < 4; j++) {
                unsigned lo = ((const unsigned*)&rb[2 * j])[q >> 1];
                unsigned hi = ((const unsigned*)&rb[2 * j + 1])[q >> 1];
                w[j] = (q & 1) ? __builtin_amdgcn_perm(hi, lo, 0x07060302)
                               : __builtin_amdgcn_perm(hi, lo, 0x05040100);
            }
            *(u32x4*)&Bs[i4 + q][kyb8] = w;
        }
        __syncthreads();
        // prefetch next tile — loads in flight during the MFMA block below
        int kn = k0 + BK;
        if (kn < KD) {
#pragma unroll
            for (int p = 0; p < NA; p++)
                ra[p] = *(const u16x4*)(Af + (size_t)(myb + p * RP) * KD + kn + kk4);
#pragma unroll
            for (int p = 0; p < NB; p++)
                rb[p] = *(const u16x4*)(Bh + (size_t)bb * KD * HWP + (size_t)(kn + kyb8 + p) * HWP + i0 + i4);
        }
#pragma unroll
        for (int ks = 0; ks < BK / 32; ks++) {
            short8 af0 = *(const short8*)&As[wm + l15][ks * 32 + quad * 8];
            short8 af1 = *(const short8*)&As[wm + 16 + l15][ks * 32 + quad * 8];
            short8 bf0 = *(const short8*)&Bs[wn + l15][ks * 32 + quad * 8];
            short8 bf1 = *(const short8*)&Bs[wn + 16 + l15][ks * 32 + quad * 8];
            acc[0][0] = __builtin_amdgcn_mfma_f32_16x16x32_bf16(af0, bf0, acc[0][0], 0, 0, 0);
            acc[0][1] = __builtin_amdgcn_mfma_f32_16x16x32_bf16(af0, bf1, acc[0][1], 0, 0, 0);
            acc[1][0] = __builtin_amdgcn_mfma_f32_16x16x32_bf16(af1, bf0, acc[1][0], 0, 0, 0);
            acc[1][1] = __builtin_amdgcn_mfma_f32_16x16x32_bf16(af1, bf1, acc[1][1], 0, 0, 0);
        }
    }

    float* outF = (float*)outp;
    unsigned short* outH = (unsigned short*)outp;
#pragma unroll
    for (int im = 0; im < 2; im++) {
#pragma unroll
        for (int r = 0; r < 4; r++) {
            int m = m0 + wm + im * 16 + quad * 4 + r;
            float bv = bias[m];
#pragma unroll
            for (int in_ = 0; in_ < 2; in_++) {
                int n = i0 + wn + in_ * 16 + l15;
                size_t idx = ((size_t)bb * MM + m) * HWP + n;
                float v = acc[im][in_][r] + bv;
                if constexpr (EPI == 1) {
                    float ge = 0.5f * v * (1.0f + erff(v * 0.7071067811865475f));
                    outH[idx] = (unsigned short)f2bf(ge);
                } else if constexpr (EPI == 3) {
                    float vr = v + resid[idx];
                    outF[idx] = vr;
                    out2[idx] = (unsigned short)f2bf(fmaf(vr, bns[m] * invs, bnb[m]));
                } else {
                    outF[idx] = v + resid[idx];
                }
            }
        }
    }
}

extern "C" void kernel_launch(void* const* d_in, const int* in_sizes, int n_in,
                              void* d_out, int out_size, void* d_ws, size_t ws_size,
                              hipStream_t stream) {
    const float* x      = (const float*)d_in[0];
    const float* bn1_g  = (const float*)d_in[1];
    const float* bn1_b  = (const float*)d_in[2];
    const float* bn2_g  = (const float*)d_in[3];
    const float* bn2_b  = (const float*)d_in[4];
    const float* qw     = (const float*)d_in[5];
    const float* kw     = (const float*)d_in[6];
    const float* vw     = (const float*)d_in[7];
    const float* out_w  = (const float*)d_in[8];
    const float* out_b  = (const float*)d_in[9];
    const float* off_dw_w = (const float*)d_in[10];
    const float* off_dw_b = (const float*)d_in[11];
    const float* off_pw_w = (const float*)d_in[12];
    const float* cpb_w1 = (const float*)d_in[13];
    const float* cpb_b1 = (const float*)d_in[14];
    const float* cpb_w2 = (const float*)d_in[15];
    const float* cpb_b2 = (const float*)d_in[16];
    const float* cpb_w3 = (const float*)d_in[17];
    const float* cpb_b3 = (const float*)d_in[18];
    const float* mlp_w1 = (const float*)d_in[19];
    const float* mlp_b1 = (const float*)d_in[20];
    const float* mlp_w2 = (const float*)d_in[21];
    const float* mlp_b2 = (const float*)d_in[22];

    float* ws = (float*)d_ws;
    unsigned short* qt = (unsigned short*)(ws + 1048576);   // 1,048,576 bf16
    float* vgrid = ws + 2097152;      // 2,048
    float* kk    = ws + 2164736;      // 65,536
    float* vv    = ws + 2230272;      // 65,536
    unsigned short* w2p = (unsigned short*)(ws + 2295808);  // 16,384 bf16
    unsigned short* ao  = (unsigned short*)(ws + 2312192);  // 1,048,576 bf16
    unsigned short* xn2 = (unsigned short*)(ws + 2836480);  // 1,048,576 bf16
    float* xo    = ws + 3360768;      // 1,048,576 floats
    float* h1of  = ws + 4409344;      // bias bf16 (1M ushorts), then h1o bf16 (4M ushorts)
    unsigned short* biasb = (unsigned short*)h1of;          // consumed by k_attn before g1 writes h1o
    unsigned short* h1o = (unsigned short*)h1of;
    unsigned short* wp  = (unsigned short*)(ws + 6506496);  // 2,392,064 ushorts
    unsigned short* qwp  = wp;
    unsigned short* owp  = wp + 32768;
    unsigned short* w1p  = wp + 294912;
    unsigned short* w2mp = wp + 1343488;

    hipLaunchKernelGGL(k_wpack, dim3(9408), dim3(256), 0, stream,
                       qw, out_w, mlp_w1, mlp_w2, cpb_w2, wp, w2p);
    hipLaunchKernelGGL(k_qgemm, dim3(256), dim3(256), 0, stream, x, bn1_g, bn1_b, qwp, qt);
    hipLaunchKernelGGL(k_offskv, dim3(1024), dim3(64), 0, stream,
                       qt, off_dw_w, off_dw_b, off_pw_w, x, bn1_g, bn1_b, kw, vw,
                       vgrid, kk, vv);
    hipLaunchKernelGGL(k_cpb, dim3(2048), dim3(256), 0, stream,
                       vgrid, w2p, cpb_w1, cpb_b1, cpb_b2, cpb_w3, cpb_b3, biasb);
    hipLaunchKernelGGL(k_attn, dim3(256), dim3(256), 0, stream, qt, kk, vv, biasb, ao);
    // out projection: M=512, K=512 (BK=128), B=ao bf16, resid=x -> xo + xn2(BN2 bf16)
    k_gemm<3, 512, 128, 8><<<dim3(256), dim3(256), 0, stream>>>(
        owp, ao, x, out_b, xo, xn2, bn2_g, bn2_b);
    // MLP1: M=2048, K=512 (BK=128), B=xn2 bf16, gelu -> h1o bf16
    k_gemm<1, 512, 128, 32><<<dim3(1024), dim3(256), 0, stream>>>(
        w1p, xn2, nullptr, mlp_b1, h1o, nullptr, nullptr, nullptr);
    // MLP2: M=512, K=2048 (BK=128), B=h1o bf16, resid=xo -> d_out
    k_gemm<2, 2048, 128, 8><<<dim3(256), dim3(256), 0, stream>>>(
        w2mp, h1o, xo, mlp_b2, d_out, nullptr, nullptr, nullptr);
}

// Round 15
// 234.209 us; speedup vs baseline: 1.1537x; 1.0226x over previous
//
#include <hip/hip_runtime.h>
#include <hip/hip_bf16.h>
#include <math.h>

// Problem constants
#define BB 2
#define CC 512
#define HH 32
#define WW 32
#define HWP 1024      // H*W
#define GG 8
#define DH 64
#define HD 8
#define WD 8
#define JJ 64         // HD*WD
#define BG 16         // BB*GG
#define EPS 1e-5f

typedef __attribute__((ext_vector_type(8))) short short8;
typedef __attribute__((ext_vector_type(4))) short s16x4;
typedef __attribute__((ext_vector_type(4))) float f32x4;
typedef __attribute__((ext_vector_type(4))) unsigned short u16x4;
typedef __attribute__((ext_vector_type(4))) unsigned int u32x4;

// RNE float -> bf16 bits
static __device__ __forceinline__ short f2bf(float x) {
    unsigned u = __builtin_bit_cast(unsigned, x);
    u += 0x7FFFu + ((u >> 16) & 1u);
    return (short)(u >> 16);
}
static __device__ __forceinline__ float bf2f(unsigned short h) {
    return __builtin_bit_cast(float, (unsigned)h << 16);
}

// ---------------- K0: pre-pack weights ----------------
// bf16: qw|out_w|mlp_w1|mlp_w2 -> wp; cpb_w2 -> w2p (frag order).
// fp32 transposes (bit-exact copies, coalesced for k_offskv):
//   kwt/vwt[g][c][o] = kw/vw[(g*64+o)*64+c];  dwt[k][ch] = dww[ch*36+k].
__global__ void k_wpack(const float* __restrict__ qw, const float* __restrict__ ow,
                        const float* __restrict__ w1, const float* __restrict__ w2,
                        const float* __restrict__ cw2, const float* __restrict__ kw,
                        const float* __restrict__ vw, const float* __restrict__ dww,
                        unsigned short* __restrict__ wp, unsigned short* __restrict__ w2p,
                        float* __restrict__ kwt, float* __restrict__ vwt,
                        float* __restrict__ dwt) {
    int idx = blockIdx.x * 256 + threadIdx.x;
    if (idx < 2392064) {
        float v;
        if (idx < 32768) v = qw[idx];
        else if (idx < 294912) v = ow[idx - 32768];
        else if (idx < 1343488) v = w1[idx - 294912];
        else v = w2[idx - 1343488];
        wp[idx] = (unsigned short)f2bf(v);
    } else if (idx < 2408448) {
        int i2 = idx - 2392064;
        int k = i2 >> 7, n = i2 & 127;
        int dest = ((((n >> 4) * 4 + (k >> 5)) * 64) + (((k >> 3) & 3) * 16) + (n & 15)) * 8 + (k & 7);
        w2p[dest] = (unsigned short)f2bf(cw2[i2]);
    } else if (idx < 2441216) {
        int i2 = idx - 2408448;                 // g*4096 + c*64 + o
        int o = i2 & 63, c = (i2 >> 6) & 63, g = i2 >> 12;
        kwt[i2] = kw[(size_t)(g * 64 + o) * 64 + c];
    } else if (idx < 2473984) {
        int i2 = idx - 2441216;
        int o = i2 & 63, c = (i2 >> 6) & 63, g = i2 >> 12;
        vwt[i2] = vw[(size_t)(g * 64 + o) * 64 + c];
    } else if (idx < 2476288) {
        int i2 = idx - 2473984;                 // k*64 + ch
        int ch = i2 & 63, k = i2 >> 6;
        dwt[i2] = dww[ch * 36 + k];
    }
}

// ---------------- K2: q grouped 1x1 conv via MFMA -> qt[bg][i][ch] bf16 ----------------
__global__ __launch_bounds__(256) void k_qgemm(
    const float* __restrict__ x, const float* __restrict__ g1,
    const float* __restrict__ b1, const unsigned short* __restrict__ qwp,
    unsigned short* __restrict__ qt) {
    __shared__ __align__(16) short As[64][72];
    __shared__ __align__(16) short Bs[64][72];
    int blk = blockIdx.x;
    int bg = blk >> 4, nt = blk & 15;
    int b = bg >> 3, g = bg & 7;
    int i0 = nt * 64;
    int tid = threadIdx.x, lane = tid & 63, wv = tid >> 6;
    int wm = (wv >> 1) * 32, wn = (wv & 1) * 32;
    int l15 = lane & 15, quad = lane >> 4;
    const float invs = 1.0f / sqrtf(1.0f + EPS);
    {
        int c4 = (tid & 15) * 4;
        int ob = tid >> 4;
#pragma unroll
        for (int p = 0; p < 4; p++) {
            int o = ob + p * 16;
            u16x4 v = *(const u16x4*)(qwp + (size_t)(g * 64 + o) * 64 + c4);
            *(u16x4*)&As[o][c4] = v;
        }
    }
    {
        int i4 = (tid & 15) * 4;
        int cb = tid >> 4;
#pragma unroll
        for (int p = 0; p < 4; p++) {
            int c = cb + p * 16;
            f32x4 v = *(const f32x4*)(x + (size_t)(b * CC + g * 64 + c) * HWP + i0 + i4);
            float sc = g1[g * 64 + c] * invs;
            float sh = b1[g * 64 + c];
            Bs[i4 + 0][c] = f2bf(fmaf(v.x, sc, sh));
            Bs[i4 + 1][c] = f2bf(fmaf(v.y, sc, sh));
            Bs[i4 + 2][c] = f2bf(fmaf(v.z, sc, sh));
            Bs[i4 + 3][c] = f2bf(fmaf(v.w, sc, sh));
        }
    }
    __syncthreads();
    f32x4 acc[2][2];
#pragma unroll
    for (int a = 0; a < 2; a++)
#pragma unroll
        for (int c = 0; c < 2; c++) acc[a][c] = (f32x4){0.f, 0.f, 0.f, 0.f};
#pragma unroll
    for (int ks = 0; ks < 2; ks++) {
        short8 af0 = *(const short8*)&As[wm + l15][ks * 32 + quad * 8];
        short8 af1 = *(const short8*)&As[wm + 16 + l15][ks * 32 + quad * 8];
        short8 bf0 = *(const short8*)&Bs[wn + l15][ks * 32 + quad * 8];
        short8 bf1 = *(const short8*)&Bs[wn + 16 + l15][ks * 32 + quad * 8];
        acc[0][0] = __builtin_amdgcn_mfma_f32_16x16x32_bf16(af0, bf0, acc[0][0], 0, 0, 0);
        acc[0][1] = __builtin_amdgcn_mfma_f32_16x16x32_bf16(af0, bf1, acc[0][1], 0, 0, 0);
        acc[1][0] = __builtin_amdgcn_mfma_f32_16x16x32_bf16(af1, bf0, acc[1][0], 0, 0, 0);
        acc[1][1] = __builtin_amdgcn_mfma_f32_16x16x32_bf16(af1, bf1, acc[1][1], 0, 0, 0);
    }
    // transpose via LDS (reuse As) -> coalesced qt[bg][i][ch] bf16 stores
    __syncthreads();
#pragma unroll
    for (int im = 0; im < 2; im++)
#pragma unroll
        for (int r = 0; r < 4; r++) {
            int m = wm + im * 16 + quad * 4 + r;
#pragma unroll
            for (int in_ = 0; in_ < 2; in_++) {
                int n = wn + in_ * 16 + l15;
                As[n][m] = f2bf(acc[im][in_][r]);
            }
        }
    __syncthreads();
    {
        int n = tid >> 2;
        int c0 = (tid & 3) * 16;
        short8 a = *(const short8*)&As[n][c0];
        short8 c = *(const short8*)&As[n][c0 + 8];
        unsigned short* dst = qt + ((size_t)bg * 1024 + i0 + n) * 64 + c0;
        *(short8*)dst = a;
        *(short8*)(dst + 8) = c;
    }
}

// ---------------- K3+K4+K5 fused: offsets -> vgrid -> grid_sample(BN1) -> k/v conv ----------------
// v2: coalesced transposed weights (dwt, kwt, vwt); bf16 k/v output (bit-exact
// vs converting in k_attn).
__global__ __launch_bounds__(64) void k_offskv(
    const unsigned short* __restrict__ qt, const float* __restrict__ dwt,
    const float* __restrict__ dwb, const float* __restrict__ pw,
    const float* __restrict__ x, const float* __restrict__ g1,
    const float* __restrict__ b1, const float* __restrict__ kwt,
    const float* __restrict__ vwt, float* __restrict__ vgrid,
    unsigned short* __restrict__ kkh, unsigned short* __restrict__ vvh) {
    __shared__ float sm[64];
    int blk = blockIdx.x;
    int bg = blk >> 6;
    int hd = (blk >> 3) & 7;
    int wd = blk & 7;
    int g = bg & 7, b = bg >> 3;
    int ch = threadIdx.x;
    const unsigned short* qb = qt + (size_t)bg * 65536;
    float acc = 0.f;
#pragma unroll
    for (int kh = 0; kh < 6; kh++) {
        int hin = hd * 4 - 1 + kh;
        if (hin < 0 || hin >= HH) continue;
#pragma unroll
        for (int kw_ = 0; kw_ < 6; kw_++) {
            int win = wd * 4 - 1 + kw_;
            if (win < 0 || win >= WW) continue;
            acc = fmaf(bf2f(qb[(hin * WW + win) * 64 + ch]),
                       dwt[(kh * 6 + kw_) * 64 + ch], acc);
        }
    }
    acc += dwb[ch];
    float ge = 0.5f * acc * (1.0f + erff(acc * 0.7071067811865475f));
    float p0 = ge * pw[ch];
    float p1 = ge * pw[64 + ch];
#pragma unroll
    for (int off = 32; off; off >>= 1) {
        p0 += __shfl_xor(p0, off);
        p1 += __shfl_xor(p1, off);
    }
    float nx = 2.0f * ((float)wd + tanhf(p0) * 4.0f) / 7.0f - 1.0f;
    float ny = 2.0f * ((float)hd + tanhf(p1) * 4.0f) / 7.0f - 1.0f;
    if (ch == 0) {
        vgrid[blk * 2] = nx;
        vgrid[blk * 2 + 1] = ny;
    }
    {
        int cg = g * 64 + ch;
        const float invs = 1.0f / sqrtf(1.0f + EPS);
        float s = g1[cg] * invs;
        float bv = b1[cg];
        float gx = (nx + 1.0f) * 16.0f - 0.5f;
        float gy = (ny + 1.0f) * 16.0f - 0.5f;
        float x0f = floorf(gx), y0f = floorf(gy);
        float wx = gx - x0f, wy = gy - y0f;
        int x0 = (int)x0f, y0 = (int)y0f;
        const float* im = x + (size_t)(b * CC + cg) * HWP;
        float sx = 0.f, sw = 0.f;
        float w00 = (1 - wx) * (1 - wy), w01 = wx * (1 - wy);
        float w10 = (1 - wx) * wy, w11 = wx * wy;
        if (x0 >= 0 && x0 < WW && y0 >= 0 && y0 < HH)                 { sx += w00 * im[y0 * WW + x0];           sw += w00; }
        if (x0 + 1 >= 0 && x0 + 1 < WW && y0 >= 0 && y0 < HH)         { sx += w01 * im[y0 * WW + x0 + 1];       sw += w01; }
        if (x0 >= 0 && x0 < WW && y0 + 1 >= 0 && y0 + 1 < HH)         { sx += w10 * im[(y0 + 1) * WW + x0];     sw += w10; }
        if (x0 + 1 >= 0 && x0 + 1 < WW && y0 + 1 >= 0 && y0 + 1 < HH) { sx += w11 * im[(y0 + 1) * WW + x0 + 1]; sw += w11; }
        sm[ch] = s * sx + bv * sw;
    }
    __syncthreads();
    int j = blk & 63;
    const float* kwr = kwt + g * 4096 + ch;     // lane-contiguous per c-iter
    const float* vwr = vwt + g * 4096 + ch;
    float ak = 0.f, av = 0.f;
#pragma unroll
    for (int c = 0; c < 64; c++) {
        float tv = sm[c];
        ak = fmaf(tv, kwr[c * 64], ak);
        av = fmaf(tv, vwr[c * 64], av);
    }
    kkh[(size_t)bg * 4096 + j * 64 + ch] = (unsigned short)f2bf(ak);
    vvh[(size_t)bg * 4096 + j * 64 + ch] = (unsigned short)f2bf(av);
}

// ---------------- K6: CPB bias MLP via bf16 MFMA (v7, frozen ~79.7us) ----------------
__global__ __launch_bounds__(256) void k_cpb(
    const float* __restrict__ vgrid, const unsigned short* __restrict__ w2p,
    const float* __restrict__ w1, const float* __restrict__ b1,
    const float* __restrict__ b2, const float* __restrict__ w3,
    const float* __restrict__ b3, unsigned short* __restrict__ bias) {
    __shared__ __align__(16) short w2fs[16384];   // exactly 32768 B -> 5 blocks/CU
    int tid = threadIdx.x;
    {
        const u32x4* src = (const u32x4*)w2p;
        u32x4* dst = (u32x4*)w2fs;
        for (int c = tid; c < 2048; c += 256) dst[c] = src[c];
    }
    float bias3 = b3[0];
    __syncthreads();

    int lane = tid & 63;
    int wv = tid >> 6;
    int l15 = lane & 15;
    int quad = lane >> 4;

#pragma unroll 1
    for (int it = 0; it < 4; it++) {
        int p = (blockIdx.x * 4 + it) * 4 + wv;
        int pu = __builtin_amdgcn_readfirstlane(p);      // wave-uniform -> SGPR
        int cofs = (int)((unsigned)pu >> 20);            // runtime 0, opaque, scalar
        int bg = p >> 11;
        int i = (p >> 1) & 1023;
        int jbase = (p & 1) * 32;
        int hi = i >> 5, wi = i & 31;
        float qx = 2.0f * (float)wi / 31.0f - 1.0f;
        float qy = 2.0f * (float)hi / 31.0f - 1.0f;

        int jA = jbase + l15;
        float gkxA = vgrid[(bg * 64 + jA) * 2];
        float gkyA = vgrid[(bg * 64 + jA) * 2 + 1];
        float gkxB = vgrid[(bg * 64 + jA + 16) * 2];
        float gkyB = vgrid[(bg * 64 + jA + 16) * 2 + 1];
        float p0 = qx - gkxA, p1 = qy - gkyA;
        float s0a = copysignf(log1pf(fabsf(p0)), p0);
        float s1a = copysignf(log1pf(fabsf(p1)), p1);
        p0 = qx - gkxB; p1 = qy - gkyB;
        float s0b = copysignf(log1pf(fabsf(p0)), p0);
        float s1b = copysignf(log1pf(fabsf(p1)), p1);

        short8 hA[4], hB[4];
#pragma unroll
        for (int kc = 0; kc < 4; kc++) {
            f32x4 cu0 = *(const f32x4*)(w1 + cofs + kc * 32 + quad * 8);
            f32x4 cu1 = *(const f32x4*)(w1 + cofs + kc * 32 + quad * 8 + 4);
            f32x4 cv0 = *(const f32x4*)(w1 + cofs + 128 + kc * 32 + quad * 8);
            f32x4 cv1 = *(const f32x4*)(w1 + cofs + 128 + kc * 32 + quad * 8 + 4);
            f32x4 cb0 = *(const f32x4*)(b1 + cofs + kc * 32 + quad * 8);
            f32x4 cb1 = *(const f32x4*)(b1 + cofs + kc * 32 + quad * 8 + 4);
            u32x4 pa, pb;
#pragma unroll
            for (int j2 = 0; j2 < 4; j2++) {
                int e0 = 2 * j2, e1 = 2 * j2 + 1;
                float u0 = (e0 < 4) ? cu0[e0] : cu1[e0 - 4];
                float u1 = (e1 < 4) ? cu0[e1] : cu1[e1 - 4];
                float v0 = (e0 < 4) ? cv0[e0] : cv1[e0 - 4];
                float v1 = (e1 < 4) ? cv0[e1] : cv1[e1 - 4];
                float c0 = (e0 < 4) ? cb0[e0] : cb1[e0 - 4];
                float c1 = (e1 < 4) ? cb0[e1] : cb1[e1 - 4];
                unsigned a0 = __builtin_bit_cast(unsigned,
                    fmaxf(fmaf(s0a, u0, fmaf(s1a, v0, c0)), 0.f)) + 0x8000u;
                unsigned a1 = __builtin_bit_cast(unsigned,
                    fmaxf(fmaf(s0a, u1, fmaf(s1a, v1, c1)), 0.f)) + 0x8000u;
                pa[j2] = __builtin_amdgcn_perm(a1, a0, 0x07060302);
                unsigned b0 = __builtin_bit_cast(unsigned,
                    fmaxf(fmaf(s0b, u0, fmaf(s1b, v0, c0)), 0.f)) + 0x8000u;
                unsigned b1_ = __builtin_bit_cast(unsigned,
                    fmaxf(fmaf(s0b, u1, fmaf(s1b, v1, c1)), 0.f)) + 0x8000u;
                pb[j2] = __builtin_amdgcn_perm(b1_, b0, 0x07060302);
            }
            hA[kc] = __builtin_bit_cast(short8, pa);
            hB[kc] = __builtin_bit_cast(short8, pb);
        }

        float psumA = 0.f, psumB = 0.f;
#pragma unroll 2
        for (int nt = 0; nt < 8; nt++) {
            f32x4 accA = (f32x4){0.f, 0.f, 0.f, 0.f};
            f32x4 accB = (f32x4){0.f, 0.f, 0.f, 0.f};
#pragma unroll
            for (int kc = 0; kc < 4; kc++) {
                short8 af = *(const short8*)(w2fs + (((nt * 4 + kc) * 64) + lane) * 8);
                accA = __builtin_amdgcn_mfma_f32_16x16x32_bf16(af, hA[kc], accA, 0, 0, 0);
                accB = __builtin_amdgcn_mfma_f32_16x16x32_bf16(af, hB[kc], accB, 0, 0, 0);
            }
            f32x4 b2q = *(const f32x4*)(b2 + cofs + nt * 16 + quad * 4);
            f32x4 w3q = *(const f32x4*)(w3 + cofs + nt * 16 + quad * 4);
#pragma unroll
            for (int r = 0; r < 4; r++) {
                psumA = fmaf(fmaxf(accA[r] + b2q[r], 0.f), w3q[r], psumA);
                psumB = fmaf(fmaxf(accB[r] + b2q[r], 0.f), w3q[r], psumB);
            }
        }
        psumA += __shfl_xor(psumA, 16);
        psumA += __shfl_xor(psumA, 32);
        psumB += __shfl_xor(psumB, 16);
        psumB += __shfl_xor(psumB, 32);
        if (quad == 0) {
            bias[(size_t)(p * 2 + 0) * 16 + l15] = (unsigned short)f2bf(psumA + bias3);
            bias[(size_t)(p * 2 + 1) * 16 + l15] = (unsigned short)f2bf(psumB + bias3);
        }
    }
}

// ---------------- K7: attention via MFMA (bf16 K/V inputs, perm-transpose V staging) ----------------
__global__ __launch_bounds__(256) void k_attn(
    const unsigned short* __restrict__ qt, const unsigned short* __restrict__ kkh,
    const unsigned short* __restrict__ vvh, const unsigned short* __restrict__ bias,
    unsigned short* __restrict__ ao) {
    __shared__ __align__(16) short Ks[64][72];
    __shared__ __align__(16) short Vt[64][72];
    __shared__ __align__(16) short Qs[64][72];
    __shared__ __align__(16) short Ps[4][16][72];
    int blk = blockIdx.x;
    int bg = blk >> 4;
    int chunk = blk & 15;
    int i0 = chunk * 64;
    int b = bg >> 3, g = bg & 7;
    int tid = threadIdx.x, lane = tid & 63, wv = tid >> 6;
    int l15 = lane & 15, quad = lane >> 4;

    const unsigned short* kbase = kkh + (size_t)bg * 4096;
    const unsigned short* vbase = vvh + (size_t)bg * 4096;
    // Ks: straight 16B copies
#pragma unroll
    for (int it = 0; it < 2; it++) {
        int e8 = (it * 256 + tid) * 8;
        int j = e8 >> 6, d = e8 & 63;
        u32x4 v = *(const u32x4*)(kbase + e8);
        *(u32x4*)&Ks[j][d] = v;
    }
    // Vt: in-register 8j x 4d perm transpose (threads 0..127)
    if (tid < 128) {
        int d0 = (tid & 15) * 4;
        int jb = (tid >> 4) * 8;
        u16x4 rb[8];
#pragma unroll
        for (int p = 0; p < 8; p++)
            rb[p] = *(const u16x4*)(vbase + (jb + p) * 64 + d0);
#pragma unroll
        for (int q = 0; q < 4; q++) {
            u32x4 w;
#pragma unroll
            for (int jj = 0; jj < 4; jj++) {
                unsigned lo = ((const unsigned*)&rb[2 * jj])[q >> 1];
                unsigned hi = ((const unsigned*)&rb[2 * jj + 1])[q >> 1];
                w[jj] = (q & 1) ? __builtin_amdgcn_perm(hi, lo, 0x07060302)
                                : __builtin_amdgcn_perm(hi, lo, 0x05040100);
            }
            *(u32x4*)&Vt[d0 + q][jb] = w;
        }
    }
    {
        const unsigned short* qtb = qt + ((size_t)bg * 1024 + i0) * 64;
#pragma unroll
        for (int it = 0; it < 4; it++) {
            int e4 = it * 1024 + tid * 4;
            int i = e4 >> 6, d = e4 & 63;
            u16x4 v = *(const u16x4*)(qtb + e4);
            *(u16x4*)&Qs[i][d] = v;
        }
    }
    __syncthreads();

    int iw = wv * 16;
    f32x4 Sacc[4];
#pragma unroll
    for (int nt = 0; nt < 4; nt++) Sacc[nt] = (f32x4){0.f, 0.f, 0.f, 0.f};
#pragma unroll
    for (int ks = 0; ks < 2; ks++) {
        short8 aq = *(const short8*)&Qs[iw + l15][quad * 8 + ks * 32];
#pragma unroll
        for (int nt = 0; nt < 4; nt++) {
            short8 bk = *(const short8*)&Ks[nt * 16 + l15][quad * 8 + ks * 32];
            Sacc[nt] = __builtin_amdgcn_mfma_f32_16x16x32_bf16(aq, bk, Sacc[nt], 0, 0, 0);
        }
    }
    const unsigned short* bp = bias + ((size_t)bg * 1024 + i0 + iw + quad * 4) * 64 + l15;
    float Sv[4][4];
#pragma unroll
    for (int nt = 0; nt < 4; nt++)
#pragma unroll
        for (int r = 0; r < 4; r++)
            Sv[nt][r] = fmaf(Sacc[nt][r], 0.125f, bf2f(bp[r * 64 + nt * 16]));
#pragma unroll
    for (int r = 0; r < 4; r++) {
        float m = fmaxf(fmaxf(Sv[0][r], Sv[1][r]), fmaxf(Sv[2][r], Sv[3][r]));
        m = fmaxf(m, __shfl_xor(m, 1));
        m = fmaxf(m, __shfl_xor(m, 2));
        m = fmaxf(m, __shfl_xor(m, 4));
        m = fmaxf(m, __shfl_xor(m, 8));
        float l = 0.f;
#pragma unroll
        for (int nt = 0; nt < 4; nt++) { Sv[nt][r] = expf(Sv[nt][r] - m); l += Sv[nt][r]; }
        l += __shfl_xor(l, 1);
        l += __shfl_xor(l, 2);
        l += __shfl_xor(l, 4);
        l += __shfl_xor(l, 8);
        float inv = 1.0f / l;
#pragma unroll
        for (int nt = 0; nt < 4; nt++)
            Ps[wv][quad * 4 + r][nt * 16 + l15] = f2bf(Sv[nt][r] * inv);
    }
    f32x4 Oacc[4];
#pragma unroll
    for (int nt = 0; nt < 4; nt++) Oacc[nt] = (f32x4){0.f, 0.f, 0.f, 0.f};
#pragma unroll
    for (int ks = 0; ks < 2; ks++) {
        short8 ap = *(const short8*)&Ps[wv][l15][quad * 8 + ks * 32];
#pragma unroll
        for (int nt = 0; nt < 4; nt++) {
            short8 bv = *(const short8*)&Vt[nt * 16 + l15][quad * 8 + ks * 32];
            Oacc[nt] = __builtin_amdgcn_mfma_f32_16x16x32_bf16(ap, bv, Oacc[nt], 0, 0, 0);
        }
    }
    __syncthreads();
#pragma unroll
    for (int nt = 0; nt < 4; nt++) {
        s16x4 o4 = {f2bf(Oacc[nt][0]), f2bf(Oacc[nt][1]), f2bf(Oacc[nt][2]), f2bf(Oacc[nt][3])};
        *(s16x4*)&Qs[nt * 16 + l15][iw + quad * 4] = o4;
    }
    __syncthreads();
    {
        int d = tid >> 2;
        int ic = (tid & 3) * 16;
        short8 a = *(const short8*)&Qs[d][ic];
        short8 c = *(const short8*)&Qs[d][ic + 8];
        unsigned short* dst = ao + (size_t)(b * CC + g * 64 + d) * HWP + i0 + ic;
        *(short8*)dst = a;
        *(short8*)(dst + 8) = c;
    }
}

// ---------------- K8/K10/K11: tiled bf16-MFMA GEMM, pipelined + perm-transpose B-staging ----------------
template<int EPI, int KD, int BK, int MT>
__global__ __launch_bounds__(256) void k_gemm(
    const unsigned short* __restrict__ A, const unsigned short* __restrict__ Bh,
    const float* __restrict__ resid, const float* __restrict__ bias,
    void* __restrict__ outp, unsigned short* __restrict__ out2,
    const float* __restrict__ bns, const float* __restrict__ bnb) {
    constexpr int MM = MT * 64;
    constexpr int KV4 = BK / 4;
    constexpr int RP = 256 / KV4;
    constexpr int NA = 64 / RP;
    constexpr int NB = BK / 16;
    __shared__ __align__(16) short As[64][BK + 8];
    __shared__ __align__(16) short Bs[64][BK + 8];
    int tid = threadIdx.x;
    int blk = blockIdx.x;
    int mt = blk & (MT - 1);
    int nb = blk / MT;
    int bb = nb >> 4, nt = nb & 15;
    int m0 = mt * 64, i0 = nt * 64;
    int lane = tid & 63, wv = tid >> 6;
    int wm = (wv >> 1) * 32, wn = (wv & 1) * 32;
    int l15 = lane & 15, quad = lane >> 4;
    const unsigned short* Af = A + (size_t)m0 * KD;
    const float invs = 1.0f / sqrtf(1.0f + EPS);
    int kk4 = (tid & (KV4 - 1)) * 4;
    int myb = tid / KV4;
    int i4 = (tid & 15) * 4;
    int kyb8 = (tid >> 4) * NB;

    f32x4 acc[2][2];
#pragma unroll
    for (int a = 0; a < 2; a++)
#pragma unroll
        for (int c = 0; c < 2; c++) acc[a][c] = (f32x4){0.f, 0.f, 0.f, 0.f};

    u16x4 ra[NA], rb[NB];
#pragma unroll
    for (int p = 0; p < NA; p++)
        ra[p] = *(const u16x4*)(Af + (size_t)(myb + p * RP) * KD + kk4);
#pragma unroll
    for (int p = 0; p < NB; p++)
        rb[p] = *(const u16x4*)(Bh + (size_t)bb * KD * HWP + (size_t)(kyb8 + p) * HWP + i0 + i4);

    for (int k0 = 0; k0 < KD; k0 += BK) {
        __syncthreads();
#pragma unroll
        for (int p = 0; p < NA; p++)
            *(u16x4*)&As[myb + p * RP][kk4] = ra[p];
#pragma unroll
        for (int q = 0; q < 4; q++) {
            u32x4 w;
#pragma unroll
            for (int j = 0; j < 4; j++) {
                unsigned lo = ((const unsigned*)&rb[2 * j])[q >> 1];
                unsigned hi = ((const unsigned*)&rb[2 * j + 1])[q >> 1];
                w[j] = (q & 1) ? __builtin_amdgcn_perm(hi, lo, 0x07060302)
                               : __builtin_amdgcn_perm(hi, lo, 0x05040100);
            }
            *(u32x4*)&Bs[i4 + q][kyb8] = w;
        }
        __syncthreads();
        int kn = k0 + BK;
        if (kn < KD) {
#pragma unroll
            for (int p = 0; p < NA; p++)
                ra[p] = *(const u16x4*)(Af + (size_t)(myb + p * RP) * KD + kn + kk4);
#pragma unroll
            for (int p = 0; p < NB; p++)
                rb[p] = *(const u16x4*)(Bh + (size_t)bb * KD * HWP + (size_t)(kn + kyb8 + p) * HWP + i0 + i4);
        }
#pragma unroll
        for (int ks = 0; ks < BK / 32; ks++) {
            short8 af0 = *(const short8*)&As[wm + l15][ks * 32 + quad * 8];
            short8 af1 = *(const short8*)&As[wm + 16 + l15][ks * 32 + quad * 8];
            short8 bf0 = *(const short8*)&Bs[wn + l15][ks * 32 + quad * 8];
            short8 bf1 = *(const short8*)&Bs[wn + 16 + l15][ks * 32 + quad * 8];
            acc[0][0] = __builtin_amdgcn_mfma_f32_16x16x32_bf16(af0, bf0, acc[0][0], 0, 0, 0);
            acc[0][1] = __builtin_amdgcn_mfma_f32_16x16x32_bf16(af0, bf1, acc[0][1], 0, 0, 0);
            acc[1][0] = __builtin_amdgcn_mfma_f32_16x16x32_bf16(af1, bf0, acc[1][0], 0, 0, 0);
            acc[1][1] = __builtin_amdgcn_mfma_f32_16x16x32_bf16(af1, bf1, acc[1][1], 0, 0, 0);
        }
    }

    float* outF = (float*)outp;
    unsigned short* outH = (unsigned short*)outp;
#pragma unroll
    for (int im = 0; im < 2; im++) {
#pragma unroll
        for (int r = 0; r < 4; r++) {
            int m = m0 + wm + im * 16 + quad * 4 + r;
            float bv = bias[m];
#pragma unroll
            for (int in_ = 0; in_ < 2; in_++) {
                int n = i0 + wn + in_ * 16 + l15;
                size_t idx = ((size_t)bb * MM + m) * HWP + n;
                float v = acc[im][in_][r] + bv;
                if constexpr (EPI == 1) {
                    float ge = 0.5f * v * (1.0f + erff(v * 0.7071067811865475f));
                    outH[idx] = (unsigned short)f2bf(ge);
                } else if constexpr (EPI == 3) {
                    float vr = v + resid[idx];
                    outF[idx] = vr;
                    out2[idx] = (unsigned short)f2bf(fmaf(vr, bns[m] * invs, bnb[m]));
                } else {
                    outF[idx] = v + resid[idx];
                }
            }
        }
    }
}

extern "C" void kernel_launch(void* const* d_in, const int* in_sizes, int n_in,
                              void* d_out, int out_size, void* d_ws, size_t ws_size,
                              hipStream_t stream) {
    const float* x      = (const float*)d_in[0];
    const float* bn1_g  = (const float*)d_in[1];
    const float* bn1_b  = (const float*)d_in[2];
    const float* bn2_g  = (const float*)d_in[3];
    const float* bn2_b  = (const float*)d_in[4];
    const float* qw     = (const float*)d_in[5];
    const float* kw     = (const float*)d_in[6];
    const float* vw     = (const float*)d_in[7];
    const float* out_w  = (const float*)d_in[8];
    const float* out_b  = (const float*)d_in[9];
    const float* off_dw_w = (const float*)d_in[10];
    const float* off_dw_b = (const float*)d_in[11];
    const float* off_pw_w = (const float*)d_in[12];
    const float* cpb_w1 = (const float*)d_in[13];
    const float* cpb_b1 = (const float*)d_in[14];
    const float* cpb_w2 = (const float*)d_in[15];
    const float* cpb_b2 = (const float*)d_in[16];
    const float* cpb_w3 = (const float*)d_in[17];
    const float* cpb_b3 = (const float*)d_in[18];
    const float* mlp_w1 = (const float*)d_in[19];
    const float* mlp_b1 = (const float*)d_in[20];
    const float* mlp_w2 = (const float*)d_in[21];
    const float* mlp_b2 = (const float*)d_in[22];

    float* ws = (float*)d_ws;
    unsigned short* qt = (unsigned short*)(ws + 1048576);   // 1,048,576 bf16
    float* vgrid = ws + 2097152;      // 2,048
    unsigned short* kkh = (unsigned short*)(ws + 2164736);  // 65,536 bf16
    unsigned short* vvh = (unsigned short*)(ws + 2230272);  // 65,536 bf16
    unsigned short* w2p = (unsigned short*)(ws + 2295808);  // 16,384 bf16
    unsigned short* ao  = (unsigned short*)(ws + 2312192);  // 1,048,576 bf16
    unsigned short* xn2 = (unsigned short*)(ws + 2836480);  // 1,048,576 bf16
    float* xo    = ws + 3360768;      // 1,048,576 floats
    float* h1of  = ws + 4409344;      // bias bf16 (1M ushorts), then h1o bf16 (4M ushorts)
    unsigned short* biasb = (unsigned short*)h1of;
    unsigned short* h1o = (unsigned short*)h1of;
    unsigned short* wp  = (unsigned short*)(ws + 6506496);  // 2,392,064 ushorts
    unsigned short* qwp  = wp;
    unsigned short* owp  = wp + 32768;
    unsigned short* w1p  = wp + 294912;
    unsigned short* w2mp = wp + 1343488;
    float* kwt = ws + 7702528;        // 32,768 fp32
    float* vwt = ws + 7735296;        // 32,768 fp32
    float* dwt = ws + 7768064;        // 2,304 fp32  (end: 7,770,368 floats ~31.1 MB)

    hipLaunchKernelGGL(k_wpack, dim3(9673), dim3(256), 0, stream,
                       qw, out_w, mlp_w1, mlp_w2, cpb_w2, kw, vw, off_dw_w,
                       wp, w2p, kwt, vwt, dwt);
    hipLaunchKernelGGL(k_qgemm, dim3(256), dim3(256), 0, stream, x, bn1_g, bn1_b, qwp, qt);
    hipLaunchKernelGGL(k_offskv, dim3(1024), dim3(64), 0, stream,
                       qt, dwt, off_dw_b, off_pw_w, x, bn1_g, bn1_b, kwt, vwt,
                       vgrid, kkh, vvh);
    hipLaunchKernelGGL(k_cpb, dim3(2048), dim3(256), 0, stream,
                       vgrid, w2p, cpb_w1, cpb_b1, cpb_b2, cpb_w3, cpb_b3, biasb);
    hipLaunchKernelGGL(k_attn, dim3(256), dim3(256), 0, stream, qt, kkh, vvh, biasb, ao);
    // out projection: M=512, K=512 (BK=128), B=ao bf16, resid=x -> xo + xn2(BN2 bf16)
    k_gemm<3, 512, 128, 8><<<dim3(256), dim3(256), 0, stream>>>(
        owp, ao, x, out_b, xo, xn2, bn2_g, bn2_b);
    // MLP1: M=2048, K=512 (BK=128), B=xn2 bf16, gelu -> h1o bf16
    k_gemm<1, 512, 128, 32><<<dim3(1024), dim3(256), 0, stream>>>(
        w1p, xn2, nullptr, mlp_b1, h1o, nullptr, nullptr, nullptr);
    // MLP2: M=512, K=2048 (BK=128), B=h1o bf16, resid=xo -> d_out
    k_gemm<2, 2048, 128, 8><<<dim3(256), dim3(256), 0, stream>>>(
        w2mp, h1o, xo, mlp_b2, d_out, nullptr, nullptr, nullptr);
}

// Round 16
// 226.935 us; speedup vs baseline: 1.1907x; 1.0321x over previous
//
#include <hip/hip_runtime.h>
#include <hip/hip_bf16.h>
#include <math.h>

// Problem constants
#define BB 2
#define CC 512
#define HH 32
#define WW 32
#define HWP 1024      // H*W
#define GG 8
#define DH 64
#define HD 8
#define WD 8
#define JJ 64         // HD*WD
#define BG 16         // BB*GG
#define EPS 1e-5f

typedef __attribute__((ext_vector_type(8))) short short8;
typedef __attribute__((ext_vector_type(4))) short s16x4;
typedef __attribute__((ext_vector_type(4))) float f32x4;
typedef __attribute__((ext_vector_type(4))) unsigned short u16x4;
typedef __attribute__((ext_vector_type(4))) unsigned int u32x4;

// RNE float -> bf16 bits
static __device__ __forceinline__ short f2bf(float x) {
    unsigned u = __builtin_bit_cast(unsigned, x);
    u += 0x7FFFu + ((u >> 16) & 1u);
    return (short)(u >> 16);
}
static __device__ __forceinline__ float bf2f(unsigned short h) {
    return __builtin_bit_cast(float, (unsigned)h << 16);
}

// ---------------- K0: pre-pack weights ----------------
__global__ void k_wpack(const float* __restrict__ qw, const float* __restrict__ ow,
                        const float* __restrict__ w1, const float* __restrict__ w2,
                        const float* __restrict__ cw2, const float* __restrict__ kw,
                        const float* __restrict__ vw, const float* __restrict__ dww,
                        unsigned short* __restrict__ wp, unsigned short* __restrict__ w2p,
                        float* __restrict__ kwt, float* __restrict__ vwt,
                        float* __restrict__ dwt) {
    int idx = blockIdx.x * 256 + threadIdx.x;
    if (idx < 2392064) {
        float v;
        if (idx < 32768) v = qw[idx];
        else if (idx < 294912) v = ow[idx - 32768];
        else if (idx < 1343488) v = w1[idx - 294912];
        else v = w2[idx - 1343488];
        wp[idx] = (unsigned short)f2bf(v);
    } else if (idx < 2408448) {
        int i2 = idx - 2392064;
        int k = i2 >> 7, n = i2 & 127;
        int dest = ((((n >> 4) * 4 + (k >> 5)) * 64) + (((k >> 3) & 3) * 16) + (n & 15)) * 8 + (k & 7);
        w2p[dest] = (unsigned short)f2bf(cw2[i2]);
    } else if (idx < 2441216) {
        int i2 = idx - 2408448;                 // g*4096 + c*64 + o
        int o = i2 & 63, c = (i2 >> 6) & 63, g = i2 >> 12;
        kwt[i2] = kw[(size_t)(g * 64 + o) * 64 + c];
    } else if (idx < 2473984) {
        int i2 = idx - 2441216;
        int o = i2 & 63, c = (i2 >> 6) & 63, g = i2 >> 12;
        vwt[i2] = vw[(size_t)(g * 64 + o) * 64 + c];
    } else if (idx < 2476288) {
        int i2 = idx - 2473984;                 // k*64 + ch
        int ch = i2 & 63, k = i2 >> 6;
        dwt[i2] = dww[ch * 36 + k];
    }
}

// ---------------- K2: q grouped 1x1 conv via MFMA -> qt[bg][i][ch] bf16 ----------------
__global__ __launch_bounds__(256) void k_qgemm(
    const float* __restrict__ x, const float* __restrict__ g1,
    const float* __restrict__ b1, const unsigned short* __restrict__ qwp,
    unsigned short* __restrict__ qt) {
    __shared__ __align__(16) short As[64][72];
    __shared__ __align__(16) short Bs[64][72];
    int blk = blockIdx.x;
    int bg = blk >> 4, nt = blk & 15;
    int b = bg >> 3, g = bg & 7;
    int i0 = nt * 64;
    int tid = threadIdx.x, lane = tid & 63, wv = tid >> 6;
    int wm = (wv >> 1) * 32, wn = (wv & 1) * 32;
    int l15 = lane & 15, quad = lane >> 4;
    const float invs = 1.0f / sqrtf(1.0f + EPS);
    {
        int c4 = (tid & 15) * 4;
        int ob = tid >> 4;
#pragma unroll
        for (int p = 0; p < 4; p++) {
            int o = ob + p * 16;
            u16x4 v = *(const u16x4*)(qwp + (size_t)(g * 64 + o) * 64 + c4);
            *(u16x4*)&As[o][c4] = v;
        }
    }
    {
        int i4 = (tid & 15) * 4;
        int cb = tid >> 4;
#pragma unroll
        for (int p = 0; p < 4; p++) {
            int c = cb + p * 16;
            f32x4 v = *(const f32x4*)(x + (size_t)(b * CC + g * 64 + c) * HWP + i0 + i4);
            float sc = g1[g * 64 + c] * invs;
            float sh = b1[g * 64 + c];
            Bs[i4 + 0][c] = f2bf(fmaf(v.x, sc, sh));
            Bs[i4 + 1][c] = f2bf(fmaf(v.y, sc, sh));
            Bs[i4 + 2][c] = f2bf(fmaf(v.z, sc, sh));
            Bs[i4 + 3][c] = f2bf(fmaf(v.w, sc, sh));
        }
    }
    __syncthreads();
    f32x4 acc[2][2];
#pragma unroll
    for (int a = 0; a < 2; a++)
#pragma unroll
        for (int c = 0; c < 2; c++) acc[a][c] = (f32x4){0.f, 0.f, 0.f, 0.f};
#pragma unroll
    for (int ks = 0; ks < 2; ks++) {
        short8 af0 = *(const short8*)&As[wm + l15][ks * 32 + quad * 8];
        short8 af1 = *(const short8*)&As[wm + 16 + l15][ks * 32 + quad * 8];
        short8 bf0 = *(const short8*)&Bs[wn + l15][ks * 32 + quad * 8];
        short8 bf1 = *(const short8*)&Bs[wn + 16 + l15][ks * 32 + quad * 8];
        acc[0][0] = __builtin_amdgcn_mfma_f32_16x16x32_bf16(af0, bf0, acc[0][0], 0, 0, 0);
        acc[0][1] = __builtin_amdgcn_mfma_f32_16x16x32_bf16(af0, bf1, acc[0][1], 0, 0, 0);
        acc[1][0] = __builtin_amdgcn_mfma_f32_16x16x32_bf16(af1, bf0, acc[1][0], 0, 0, 0);
        acc[1][1] = __builtin_amdgcn_mfma_f32_16x16x32_bf16(af1, bf1, acc[1][1], 0, 0, 0);
    }
    // transpose via LDS (reuse As) -> coalesced qt[bg][i][ch] bf16 stores
    __syncthreads();
#pragma unroll
    for (int im = 0; im < 2; im++)
#pragma unroll
        for (int r = 0; r < 4; r++) {
            int m = wm + im * 16 + quad * 4 + r;
#pragma unroll
            for (int in_ = 0; in_ < 2; in_++) {
                int n = wn + in_ * 16 + l15;
                As[n][m] = f2bf(acc[im][in_][r]);
            }
        }
    __syncthreads();
    {
        int n = tid >> 2;
        int c0 = (tid & 3) * 16;
        short8 a = *(const short8*)&As[n][c0];
        short8 c = *(const short8*)&As[n][c0 + 8];
        unsigned short* dst = qt + ((size_t)bg * 1024 + i0 + n) * 64 + c0;
        *(short8*)dst = a;
        *(short8*)(dst + 8) = c;
    }
}

// ---------------- K3+K4+K5 fused: offsets -> vgrid -> grid_sample(BN1) -> k/v conv ----------------
__global__ __launch_bounds__(64) void k_offskv(
    const unsigned short* __restrict__ qt, const float* __restrict__ dwt,
    const float* __restrict__ dwb, const float* __restrict__ pw,
    const float* __restrict__ x, const float* __restrict__ g1,
    const float* __restrict__ b1, const float* __restrict__ kwt,
    const float* __restrict__ vwt, float* __restrict__ vgrid,
    unsigned short* __restrict__ kkh, unsigned short* __restrict__ vvh) {
    __shared__ float sm[64];
    int blk = blockIdx.x;
    int bg = blk >> 6;
    int hd = (blk >> 3) & 7;
    int wd = blk & 7;
    int g = bg & 7, b = bg >> 3;
    int ch = threadIdx.x;
    const unsigned short* qb = qt + (size_t)bg * 65536;
    float acc = 0.f;
#pragma unroll
    for (int kh = 0; kh < 6; kh++) {
        int hin = hd * 4 - 1 + kh;
        if (hin < 0 || hin >= HH) continue;
#pragma unroll
        for (int kw_ = 0; kw_ < 6; kw_++) {
            int win = wd * 4 - 1 + kw_;
            if (win < 0 || win >= WW) continue;
            acc = fmaf(bf2f(qb[(hin * WW + win) * 64 + ch]),
                       dwt[(kh * 6 + kw_) * 64 + ch], acc);
        }
    }
    acc += dwb[ch];
    float ge = 0.5f * acc * (1.0f + erff(acc * 0.7071067811865475f));
    float p0 = ge * pw[ch];
    float p1 = ge * pw[64 + ch];
#pragma unroll
    for (int off = 32; off; off >>= 1) {
        p0 += __shfl_xor(p0, off);
        p1 += __shfl_xor(p1, off);
    }
    float nx = 2.0f * ((float)wd + tanhf(p0) * 4.0f) / 7.0f - 1.0f;
    float ny = 2.0f * ((float)hd + tanhf(p1) * 4.0f) / 7.0f - 1.0f;
    if (ch == 0) {
        vgrid[blk * 2] = nx;
        vgrid[blk * 2 + 1] = ny;
    }
    {
        int cg = g * 64 + ch;
        const float invs = 1.0f / sqrtf(1.0f + EPS);
        float s = g1[cg] * invs;
        float bv = b1[cg];
        float gx = (nx + 1.0f) * 16.0f - 0.5f;
        float gy = (ny + 1.0f) * 16.0f - 0.5f;
        float x0f = floorf(gx), y0f = floorf(gy);
        float wx = gx - x0f, wy = gy - y0f;
        int x0 = (int)x0f, y0 = (int)y0f;
        const float* im = x + (size_t)(b * CC + cg) * HWP;
        float sx = 0.f, sw = 0.f;
        float w00 = (1 - wx) * (1 - wy), w01 = wx * (1 - wy);
        float w10 = (1 - wx) * wy, w11 = wx * wy;
        if (x0 >= 0 && x0 < WW && y0 >= 0 && y0 < HH)                 { sx += w00 * im[y0 * WW + x0];           sw += w00; }
        if (x0 + 1 >= 0 && x0 + 1 < WW && y0 >= 0 && y0 < HH)         { sx += w01 * im[y0 * WW + x0 + 1];       sw += w01; }
        if (x0 >= 0 && x0 < WW && y0 + 1 >= 0 && y0 + 1 < HH)         { sx += w10 * im[(y0 + 1) * WW + x0];     sw += w10; }
        if (x0 + 1 >= 0 && x0 + 1 < WW && y0 + 1 >= 0 && y0 + 1 < HH) { sx += w11 * im[(y0 + 1) * WW + x0 + 1]; sw += w11; }
        sm[ch] = s * sx + bv * sw;
    }
    __syncthreads();
    int j = blk & 63;
    const float* kwr = kwt + g * 4096 + ch;
    const float* vwr = vwt + g * 4096 + ch;
    float ak = 0.f, av = 0.f;
#pragma unroll
    for (int c = 0; c < 64; c++) {
        float tv = sm[c];
        ak = fmaf(tv, kwr[c * 64], ak);
        av = fmaf(tv, vwr[c * 64], av);
    }
    kkh[(size_t)bg * 4096 + j * 64 + ch] = (unsigned short)f2bf(ak);
    vvh[(size_t)bg * 4096 + j * 64 + ch] = (unsigned short)f2bf(av);
}

// ---------------- K6: CPB bias MLP via bf16 MFMA (v7, frozen ~79.7us) ----------------
__global__ __launch_bounds__(256) void k_cpb(
    const float* __restrict__ vgrid, const unsigned short* __restrict__ w2p,
    const float* __restrict__ w1, const float* __restrict__ b1,
    const float* __restrict__ b2, const float* __restrict__ w3,
    const float* __restrict__ b3, unsigned short* __restrict__ bias) {
    __shared__ __align__(16) short w2fs[16384];   // exactly 32768 B -> 5 blocks/CU
    int tid = threadIdx.x;
    {
        const u32x4* src = (const u32x4*)w2p;
        u32x4* dst = (u32x4*)w2fs;
        for (int c = tid; c < 2048; c += 256) dst[c] = src[c];
    }
    float bias3 = b3[0];
    __syncthreads();

    int lane = tid & 63;
    int wv = tid >> 6;
    int l15 = lane & 15;
    int quad = lane >> 4;

#pragma unroll 1
    for (int it = 0; it < 4; it++) {
        int p = (blockIdx.x * 4 + it) * 4 + wv;
        int pu = __builtin_amdgcn_readfirstlane(p);
        int cofs = (int)((unsigned)pu >> 20);            // runtime 0, opaque, scalar
        int bg = p >> 11;
        int i = (p >> 1) & 1023;
        int jbase = (p & 1) * 32;
        int hi = i >> 5, wi = i & 31;
        float qx = 2.0f * (float)wi / 31.0f - 1.0f;
        float qy = 2.0f * (float)hi / 31.0f - 1.0f;

        int jA = jbase + l15;
        float gkxA = vgrid[(bg * 64 + jA) * 2];
        float gkyA = vgrid[(bg * 64 + jA) * 2 + 1];
        float gkxB = vgrid[(bg * 64 + jA + 16) * 2];
        float gkyB = vgrid[(bg * 64 + jA + 16) * 2 + 1];
        float p0 = qx - gkxA, p1 = qy - gkyA;
        float s0a = copysignf(log1pf(fabsf(p0)), p0);
        float s1a = copysignf(log1pf(fabsf(p1)), p1);
        p0 = qx - gkxB; p1 = qy - gkyB;
        float s0b = copysignf(log1pf(fabsf(p0)), p0);
        float s1b = copysignf(log1pf(fabsf(p1)), p1);

        short8 hA[4], hB[4];
#pragma unroll
        for (int kc = 0; kc < 4; kc++) {
            f32x4 cu0 = *(const f32x4*)(w1 + cofs + kc * 32 + quad * 8);
            f32x4 cu1 = *(const f32x4*)(w1 + cofs + kc * 32 + quad * 8 + 4);
            f32x4 cv0 = *(const f32x4*)(w1 + cofs + 128 + kc * 32 + quad * 8);
            f32x4 cv1 = *(const f32x4*)(w1 + cofs + 128 + kc * 32 + quad * 8 + 4);
            f32x4 cb0 = *(const f32x4*)(b1 + cofs + kc * 32 + quad * 8);
            f32x4 cb1 = *(const f32x4*)(b1 + cofs + kc * 32 + quad * 8 + 4);
            u32x4 pa, pb;
#pragma unroll
            for (int j2 = 0; j2 < 4; j2++) {
                int e0 = 2 * j2, e1 = 2 * j2 + 1;
                float u0 = (e0 < 4) ? cu0[e0] : cu1[e0 - 4];
                float u1 = (e1 < 4) ? cu0[e1] : cu1[e1 - 4];
                float v0 = (e0 < 4) ? cv0[e0] : cv1[e0 - 4];
                float v1 = (e1 < 4) ? cv0[e1] : cv1[e1 - 4];
                float c0 = (e0 < 4) ? cb0[e0] : cb1[e0 - 4];
                float c1 = (e1 < 4) ? cb0[e1] : cb1[e1 - 4];
                unsigned a0 = __builtin_bit_cast(unsigned,
                    fmaxf(fmaf(s0a, u0, fmaf(s1a, v0, c0)), 0.f)) + 0x8000u;
                unsigned a1 = __builtin_bit_cast(unsigned,
                    fmaxf(fmaf(s0a, u1, fmaf(s1a, v1, c1)), 0.f)) + 0x8000u;
                pa[j2] = __builtin_amdgcn_perm(a1, a0, 0x07060302);
                unsigned b0 = __builtin_bit_cast(unsigned,
                    fmaxf(fmaf(s0b, u0, fmaf(s1b, v0, c0)), 0.f)) + 0x8000u;
                unsigned b1_ = __builtin_bit_cast(unsigned,
                    fmaxf(fmaf(s0b, u1, fmaf(s1b, v1, c1)), 0.f)) + 0x8000u;
                pb[j2] = __builtin_amdgcn_perm(b1_, b0, 0x07060302);
            }
            hA[kc] = __builtin_bit_cast(short8, pa);
            hB[kc] = __builtin_bit_cast(short8, pb);
        }

        float psumA = 0.f, psumB = 0.f;
#pragma unroll 2
        for (int nt = 0; nt < 8; nt++) {
            f32x4 accA = (f32x4){0.f, 0.f, 0.f, 0.f};
            f32x4 accB = (f32x4){0.f, 0.f, 0.f, 0.f};
#pragma unroll
            for (int kc = 0; kc < 4; kc++) {
                short8 af = *(const short8*)(w2fs + (((nt * 4 + kc) * 64) + lane) * 8);
                accA = __builtin_amdgcn_mfma_f32_16x16x32_bf16(af, hA[kc], accA, 0, 0, 0);
                accB = __builtin_amdgcn_mfma_f32_16x16x32_bf16(af, hB[kc], accB, 0, 0, 0);
            }
            f32x4 b2q = *(const f32x4*)(b2 + cofs + nt * 16 + quad * 4);
            f32x4 w3q = *(const f32x4*)(w3 + cofs + nt * 16 + quad * 4);
#pragma unroll
            for (int r = 0; r < 4; r++) {
                psumA = fmaf(fmaxf(accA[r] + b2q[r], 0.f), w3q[r], psumA);
                psumB = fmaf(fmaxf(accB[r] + b2q[r], 0.f), w3q[r], psumB);
            }
        }
        psumA += __shfl_xor(psumA, 16);
        psumA += __shfl_xor(psumA, 32);
        psumB += __shfl_xor(psumB, 16);
        psumB += __shfl_xor(psumB, 32);
        if (quad == 0) {
            bias[(size_t)(p * 2 + 0) * 16 + l15] = (unsigned short)f2bf(psumA + bias3);
            bias[(size_t)(p * 2 + 1) * 16 + l15] = (unsigned short)f2bf(psumB + bias3);
        }
    }
}

// ---------------- K7: attention via MFMA -> ao_t[b][i][c] (transposed-activation output) ----------------
__global__ __launch_bounds__(256) void k_attn(
    const unsigned short* __restrict__ qt, const unsigned short* __restrict__ kkh,
    const unsigned short* __restrict__ vvh, const unsigned short* __restrict__ bias,
    unsigned short* __restrict__ ao) {
    __shared__ __align__(16) short Ks[64][72];
    __shared__ __align__(16) short Vt[64][72];
    __shared__ __align__(16) short Qs[64][72];
    __shared__ __align__(16) short Ps[4][16][72];
    int blk = blockIdx.x;
    int bg = blk >> 4;
    int chunk = blk & 15;
    int i0 = chunk * 64;
    int b = bg >> 3, g = bg & 7;
    int tid = threadIdx.x, lane = tid & 63, wv = tid >> 6;
    int l15 = lane & 15, quad = lane >> 4;

    const unsigned short* kbase = kkh + (size_t)bg * 4096;
    const unsigned short* vbase = vvh + (size_t)bg * 4096;
#pragma unroll
    for (int it = 0; it < 2; it++) {
        int e8 = (it * 256 + tid) * 8;
        int j = e8 >> 6, d = e8 & 63;
        u32x4 v = *(const u32x4*)(kbase + e8);
        *(u32x4*)&Ks[j][d] = v;
    }
    if (tid < 128) {
        int d0 = (tid & 15) * 4;
        int jb = (tid >> 4) * 8;
        u16x4 rb[8];
#pragma unroll
        for (int p = 0; p < 8; p++)
            rb[p] = *(const u16x4*)(vbase + (jb + p) * 64 + d0);
#pragma unroll
        for (int q = 0; q < 4; q++) {
            u32x4 w;
#pragma unroll
            for (int jj = 0; jj < 4; jj++) {
                unsigned lo = ((const unsigned*)&rb[2 * jj])[q >> 1];
                unsigned hi = ((const unsigned*)&rb[2 * jj + 1])[q >> 1];
                w[jj] = (q & 1) ? __builtin_amdgcn_perm(hi, lo, 0x07060302)
                                : __builtin_amdgcn_perm(hi, lo, 0x05040100);
            }
            *(u32x4*)&Vt[d0 + q][jb] = w;
        }
    }
    {
        const unsigned short* qtb = qt + ((size_t)bg * 1024 + i0) * 64;
#pragma unroll
        for (int it = 0; it < 4; it++) {
            int e4 = it * 1024 + tid * 4;
            int i = e4 >> 6, d = e4 & 63;
            u16x4 v = *(const u16x4*)(qtb + e4);
            *(u16x4*)&Qs[i][d] = v;
        }
    }
    __syncthreads();

    int iw = wv * 16;
    f32x4 Sacc[4];
#pragma unroll
    for (int nt = 0; nt < 4; nt++) Sacc[nt] = (f32x4){0.f, 0.f, 0.f, 0.f};
#pragma unroll
    for (int ks = 0; ks < 2; ks++) {
        short8 aq = *(const short8*)&Qs[iw + l15][quad * 8 + ks * 32];
#pragma unroll
        for (int nt = 0; nt < 4; nt++) {
            short8 bk = *(const short8*)&Ks[nt * 16 + l15][quad * 8 + ks * 32];
            Sacc[nt] = __builtin_amdgcn_mfma_f32_16x16x32_bf16(aq, bk, Sacc[nt], 0, 0, 0);
        }
    }
    const unsigned short* bp = bias + ((size_t)bg * 1024 + i0 + iw + quad * 4) * 64 + l15;
    float Sv[4][4];
#pragma unroll
    for (int nt = 0; nt < 4; nt++)
#pragma unroll
        for (int r = 0; r < 4; r++)
            Sv[nt][r] = fmaf(Sacc[nt][r], 0.125f, bf2f(bp[r * 64 + nt * 16]));
#pragma unroll
    for (int r = 0; r < 4; r++) {
        float m = fmaxf(fmaxf(Sv[0][r], Sv[1][r]), fmaxf(Sv[2][r], Sv[3][r]));
        m = fmaxf(m, __shfl_xor(m, 1));
        m = fmaxf(m, __shfl_xor(m, 2));
        m = fmaxf(m, __shfl_xor(m, 4));
        m = fmaxf(m, __shfl_xor(m, 8));
        float l = 0.f;
#pragma unroll
        for (int nt = 0; nt < 4; nt++) { Sv[nt][r] = expf(Sv[nt][r] - m); l += Sv[nt][r]; }
        l += __shfl_xor(l, 1);
        l += __shfl_xor(l, 2);
        l += __shfl_xor(l, 4);
        l += __shfl_xor(l, 8);
        float inv = 1.0f / l;
#pragma unroll
        for (int nt = 0; nt < 4; nt++)
            Ps[wv][quad * 4 + r][nt * 16 + l15] = f2bf(Sv[nt][r] * inv);
    }
    f32x4 Oacc[4];
#pragma unroll
    for (int nt = 0; nt < 4; nt++) Oacc[nt] = (f32x4){0.f, 0.f, 0.f, 0.f};
#pragma unroll
    for (int ks = 0; ks < 2; ks++) {
        short8 ap = *(const short8*)&Ps[wv][l15][quad * 8 + ks * 32];
#pragma unroll
        for (int nt = 0; nt < 4; nt++) {
            short8 bv = *(const short8*)&Vt[nt * 16 + l15][quad * 8 + ks * 32];
            Oacc[nt] = __builtin_amdgcn_mfma_f32_16x16x32_bf16(ap, bv, Oacc[nt], 0, 0, 0);
        }
    }
    // O is [i][d] per-lane (i = iw+quad*4+r, d = nt*16+l15) -> write Qs[i][d],
    // then coalesced rows to ao_t[b][i][g*64+d].
    __syncthreads();
#pragma unroll
    for (int nt = 0; nt < 4; nt++)
#pragma unroll
        for (int r = 0; r < 4; r++)
            Qs[iw + quad * 4 + r][nt * 16 + l15] = f2bf(Oacc[nt][r]);
    __syncthreads();
    {
        int il = tid >> 2;
        int c0 = (tid & 3) * 16;
        short8 a = *(const short8*)&Qs[il][c0];
        short8 c = *(const short8*)&Qs[il][c0 + 8];
        unsigned short* dst = ao + ((size_t)b * 1024 + i0 + il) * 512 + g * 64 + c0;
        *(short8*)dst = a;
        *(short8*)(dst + 8) = c;
    }
}

// ---------------- K8/K10/K11: tiled bf16-MFMA GEMM, transposed-activation B ----------------
// B is act_t[b][i][k] (row-major over k) -> B-staging identical to A-staging:
// straight u16x4 copies, conflict-free. No transpose anywhere in the K-loop.
// EPI 0/2: +resid fp32 [m][i]. EPI 1: gelu -> out2 bf16 [i][m] (LDS bounce).
// EPI 3: +resid fp32 [m][i] AND bf16(BN2) -> out2 [i][m] (LDS bounce).
template<int EPI, int KD, int BK, int MT>
__global__ __launch_bounds__(256) void k_gemm(
    const unsigned short* __restrict__ A, const unsigned short* __restrict__ Bt,
    const float* __restrict__ resid, const float* __restrict__ bias,
    void* __restrict__ outp, unsigned short* __restrict__ out2,
    const float* __restrict__ bns, const float* __restrict__ bnb) {
    constexpr int MM = MT * 64;
    constexpr int KV4 = BK / 4;        // u16x4 chunks per row
    constexpr int RP = 256 / KV4;      // rows per pass
    constexpr int NA = 64 / RP;        // loads per thread per operand
    __shared__ __align__(16) short As[64][BK + 8];
    __shared__ __align__(16) short Bs[64][BK + 8];
    int tid = threadIdx.x;
    int blk = blockIdx.x;
    int mt = blk & (MT - 1);
    int nb = blk / MT;
    int bb = nb >> 4, nt = nb & 15;
    int m0 = mt * 64, i0 = nt * 64;
    int lane = tid & 63, wv = tid >> 6;
    int wm = (wv >> 1) * 32, wn = (wv & 1) * 32;
    int l15 = lane & 15, quad = lane >> 4;
    const unsigned short* Af = A + (size_t)m0 * KD;
    const unsigned short* Bf = Bt + ((size_t)bb * HWP + i0) * KD;
    const float invs = 1.0f / sqrtf(1.0f + EPS);
    int kk4 = (tid & (KV4 - 1)) * 4;
    int myb = tid / KV4;

    f32x4 acc[2][2];
#pragma unroll
    for (int a = 0; a < 2; a++)
#pragma unroll
        for (int c = 0; c < 2; c++) acc[a][c] = (f32x4){0.f, 0.f, 0.f, 0.f};

    u16x4 ra[NA], rb[NA];
#pragma unroll
    for (int p = 0; p < NA; p++) {
        ra[p] = *(const u16x4*)(Af + (size_t)(myb + p * RP) * KD + kk4);
        rb[p] = *(const u16x4*)(Bf + (size_t)(myb + p * RP) * KD + kk4);
    }

    for (int k0 = 0; k0 < KD; k0 += BK) {
        __syncthreads();
#pragma unroll
        for (int p = 0; p < NA; p++) {
            *(u16x4*)&As[myb + p * RP][kk4] = ra[p];
            *(u16x4*)&Bs[myb + p * RP][kk4] = rb[p];
        }
        __syncthreads();
        int kn = k0 + BK;
        if (kn < KD) {
#pragma unroll
            for (int p = 0; p < NA; p++) {
                ra[p] = *(const u16x4*)(Af + (size_t)(myb + p * RP) * KD + kn + kk4);
                rb[p] = *(const u16x4*)(Bf + (size_t)(myb + p * RP) * KD + kn + kk4);
            }
        }
#pragma unroll
        for (int ks = 0; ks < BK / 32; ks++) {
            short8 af0 = *(const short8*)&As[wm + l15][ks * 32 + quad * 8];
            short8 af1 = *(const short8*)&As[wm + 16 + l15][ks * 32 + quad * 8];
            short8 bf0 = *(const short8*)&Bs[wn + l15][ks * 32 + quad * 8];
            short8 bf1 = *(const short8*)&Bs[wn + 16 + l15][ks * 32 + quad * 8];
            acc[0][0] = __builtin_amdgcn_mfma_f32_16x16x32_bf16(af0, bf0, acc[0][0], 0, 0, 0);
            acc[0][1] = __builtin_amdgcn_mfma_f32_16x16x32_bf16(af0, bf1, acc[0][1], 0, 0, 0);
            acc[1][0] = __builtin_amdgcn_mfma_f32_16x16x32_bf16(af1, bf0, acc[1][0], 0, 0, 0);
            acc[1][1] = __builtin_amdgcn_mfma_f32_16x16x32_bf16(af1, bf1, acc[1][1], 0, 0, 0);
        }
    }

    float* outF = (float*)outp;
    if constexpr (EPI == 1 || EPI == 3) __syncthreads();   // done reading As
#pragma unroll
    for (int im = 0; im < 2; im++) {
#pragma unroll
        for (int r = 0; r < 4; r++) {
            int m = m0 + wm + im * 16 + quad * 4 + r;
            int ml = wm + im * 16 + quad * 4 + r;
            float bv = bias[m];
#pragma unroll
            for (int in_ = 0; in_ < 2; in_++) {
                int nl = wn + in_ * 16 + l15;
                int n = i0 + nl;
                size_t idx = ((size_t)bb * MM + m) * HWP + n;
                float v = acc[im][in_][r] + bv;
                if constexpr (EPI == 1) {
                    float ge = 0.5f * v * (1.0f + erff(v * 0.7071067811865475f));
                    As[nl][ml] = f2bf(ge);
                } else if constexpr (EPI == 3) {
                    float vr = v + resid[idx];
                    outF[idx] = vr;
                    As[nl][ml] = f2bf(fmaf(vr, bns[m] * invs, bnb[m]));
                } else {
                    outF[idx] = v + resid[idx];
                }
            }
        }
    }
    if constexpr (EPI == 1 || EPI == 3) {
        __syncthreads();
        int il = tid >> 2;
        int c0 = (tid & 3) * 16;
        short8 a = *(const short8*)&As[il][c0];
        short8 c = *(const short8*)&As[il][c0 + 8];
        unsigned short* dst = out2 + ((size_t)bb * HWP + i0 + il) * MM + m0 + c0;
        *(short8*)dst = a;
        *(short8*)(dst + 8) = c;
    }
}

extern "C" void kernel_launch(void* const* d_in, const int* in_sizes, int n_in,
                              void* d_out, int out_size, void* d_ws, size_t ws_size,
                              hipStream_t stream) {
    const float* x      = (const float*)d_in[0];
    const float* bn1_g  = (const float*)d_in[1];
    const float* bn1_b  = (const float*)d_in[2];
    const float* bn2_g  = (const float*)d_in[3];
    const float* bn2_b  = (const float*)d_in[4];
    const float* qw     = (const float*)d_in[5];
    const float* kw     = (const float*)d_in[6];
    const float* vw     = (const float*)d_in[7];
    const float* out_w  = (const float*)d_in[8];
    const float* out_b  = (const float*)d_in[9];
    const float* off_dw_w = (const float*)d_in[10];
    const float* off_dw_b = (const float*)d_in[11];
    const float* off_pw_w = (const float*)d_in[12];
    const float* cpb_w1 = (const float*)d_in[13];
    const float* cpb_b1 = (const float*)d_in[14];
    const float* cpb_w2 = (const float*)d_in[15];
    const float* cpb_b2 = (const float*)d_in[16];
    const float* cpb_w3 = (const float*)d_in[17];
    const float* cpb_b3 = (const float*)d_in[18];
    const float* mlp_w1 = (const float*)d_in[19];
    const float* mlp_b1 = (const float*)d_in[20];
    const float* mlp_w2 = (const float*)d_in[21];
    const float* mlp_b2 = (const float*)d_in[22];

    float* ws = (float*)d_ws;
    unsigned short* qt = (unsigned short*)(ws + 1048576);   // 1,048,576 bf16
    float* vgrid = ws + 2097152;      // 2,048
    unsigned short* kkh = (unsigned short*)(ws + 2164736);  // 65,536 bf16
    unsigned short* vvh = (unsigned short*)(ws + 2230272);  // 65,536 bf16
    unsigned short* w2p = (unsigned short*)(ws + 2295808);  // 16,384 bf16
    unsigned short* ao  = (unsigned short*)(ws + 2312192);  // ao_t: 1,048,576 bf16
    unsigned short* xn2 = (unsigned short*)(ws + 2836480);  // xn2_t: 1,048,576 bf16
    float* xo    = ws + 3360768;      // 1,048,576 floats
    float* h1of  = ws + 4409344;      // bias bf16 (1M ushorts), then h1o_t bf16 (4M ushorts)
    unsigned short* biasb = (unsigned short*)h1of;          // consumed by k_attn before mlp1 writes h1o
    unsigned short* h1o = (unsigned short*)h1of;
    unsigned short* wp  = (unsigned short*)(ws + 6506496);  // 2,392,064 ushorts
    unsigned short* qwp  = wp;
    unsigned short* owp  = wp + 32768;
    unsigned short* w1p  = wp + 294912;
    unsigned short* w2mp = wp + 1343488;
    float* kwt = ws + 7702528;        // 32,768 fp32
    float* vwt = ws + 7735296;        // 32,768 fp32
    float* dwt = ws + 7768064;        // 2,304 fp32

    hipLaunchKernelGGL(k_wpack, dim3(9673), dim3(256), 0, stream,
                       qw, out_w, mlp_w1, mlp_w2, cpb_w2, kw, vw, off_dw_w,
                       wp, w2p, kwt, vwt, dwt);
    hipLaunchKernelGGL(k_qgemm, dim3(256), dim3(256), 0, stream, x, bn1_g, bn1_b, qwp, qt);
    hipLaunchKernelGGL(k_offskv, dim3(1024), dim3(64), 0, stream,
                       qt, dwt, off_dw_b, off_pw_w, x, bn1_g, bn1_b, kwt, vwt,
                       vgrid, kkh, vvh);
    hipLaunchKernelGGL(k_cpb, dim3(2048), dim3(256), 0, stream,
                       vgrid, w2p, cpb_w1, cpb_b1, cpb_b2, cpb_w3, cpb_b3, biasb);
    hipLaunchKernelGGL(k_attn, dim3(256), dim3(256), 0, stream, qt, kkh, vvh, biasb, ao);
    // out projection: M=512, K=512, B=ao_t -> xo (fp32 [m][i]) + xn2_t (bf16 [i][m])
    k_gemm<3, 512, 128, 8><<<dim3(256), dim3(256), 0, stream>>>(
        owp, ao, x, out_b, xo, xn2, bn2_g, bn2_b);
    // MLP1: M=2048, K=512, B=xn2_t, gelu -> h1o_t (bf16 [i][m])
    k_gemm<1, 512, 128, 32><<<dim3(1024), dim3(256), 0, stream>>>(
        w1p, xn2, nullptr, mlp_b1, nullptr, h1o, nullptr, nullptr);
    // MLP2: M=512, K=2048, B=h1o_t, resid=xo -> d_out (fp32 [m][i])
    k_gemm<2, 2048, 128, 8><<<dim3(256), dim3(256), 0, stream>>>(
        w2mp, h1o, xo, mlp_b2, d_out, nullptr, nullptr, nullptr);
}